// Round 5
// baseline (169.583 us; speedup 1.0000x reference)
//
#include <hip/hip_runtime.h>
#include <math.h>

#define NPOS  32768      // B*H*W
#define CDIM  128
#define HS    64
#define WSZ   64

typedef __bf16 bf8_t  __attribute__((ext_vector_type(8)));
typedef float  f32x4  __attribute__((ext_vector_type(4)));

__device__ __forceinline__ float gelu_exact(float x) {
    return 0.5f * x * (1.0f + erff(x * 0.70710678118654752f));
}

__device__ __forceinline__ void hilo(float v, unsigned& h, unsigned& l) {
    __bf16 hb = (__bf16)v;
    h = (unsigned)__builtin_bit_cast(unsigned short, hb);
    __bf16 lb = (__bf16)(v - (float)hb);
    l = (unsigned)__builtin_bit_cast(unsigned short, lb);
}

__device__ __forceinline__ void pack8(const float* v, uint4& hi, uint4& lo) {
    unsigned hh[8], ll[8];
    #pragma unroll
    for (int i = 0; i < 8; ++i) hilo(v[i], hh[i], ll[i]);
    hi = make_uint4(hh[0] | (hh[1] << 16), hh[2] | (hh[3] << 16),
                    hh[4] | (hh[5] << 16), hh[6] | (hh[7] << 16));
    lo = make_uint4(ll[0] | (ll[1] << 16), ll[2] | (ll[3] << 16),
                    ll[4] | (ll[5] << 16), ll[6] | (ll[7] << 16));
}

// ---------------------------------------------------------------------------
// A-frag layout (K=KC*32): ushort buffer; block(rt,kc) at (rt*KC+kc)*1024,
// hi elem: lane*8 + i  (lane = (row%16) + ((k%32)/8)*16, i = k%8), lo at +512.
// ---------------------------------------------------------------------------

// K_aprep: fp32 row-major [32768][128] -> frag hi/lo. grid 2048, block 256.
__global__ __launch_bounds__(256) void k_aprep(
    const float* __restrict__ src, unsigned short* __restrict__ dst)
{
    int idx = blockIdx.x * 256 + threadIdx.x;   // 32768*16
    int r = idx >> 4, k8 = (idx & 15) * 8;
    float t[8];
    *(float4*)(t)     = *(const float4*)(src + (size_t)r * 128 + k8);
    *(float4*)(t + 4) = *(const float4*)(src + (size_t)r * 128 + k8 + 4);
    uint4 hi, lo;
    pack8(t, hi, lo);
    int rt = r >> 4, kc = k8 >> 5, lp = (r & 15) + ((k8 & 31) >> 3) * 16;
    size_t base = ((size_t)rt * 4 + kc) * 1024 + lp * 8;
    *(uint4*)(dst + base)       = hi;
    *(uint4*)(dst + base + 512) = lo;
}

// K_border: zero the 1-px ring of xpad[b][66][66][128]. grid 260, block 256.
__global__ __launch_bounds__(256) void k_border(float* __restrict__ xpad)
{
    int idx = blockIdx.x * 256 + threadIdx.x;  // 8*260*32 = 66560
    int c4 = (idx & 31) * 4;
    int cell = idx >> 5;                       // 0..2079
    int b = cell / 260, r = cell % 260;
    int h, w;
    if (r < 66)       { h = 0;  w = r; }
    else if (r < 132) { h = 65; w = r - 66; }
    else { int rr = r - 132; h = 1 + (rr >> 1); w = (rr & 1) * 65; }
    size_t o = (((size_t)b * 66 + h) * 66 + w) * 128 + c4;
    *(float4*)(xpad + o) = make_float4(0.f, 0.f, 0.f, 0.f);
}

// ---------------------------------------------------------------------------
// K1: depthwise 3x3 conv (NHWC) + per-block partial BN sums
// ---------------------------------------------------------------------------
__global__ __launch_bounds__(256) void k_dwconv(
    const float* __restrict__ inp, const float* __restrict__ dww,
    const float* __restrict__ dwb, float* __restrict__ ydw,
    float* __restrict__ psum, float* __restrict__ psq)
{
    int blk = blockIdx.x;            // b*64 + h
    int b = blk >> 6, h = blk & 63;
    int tid = threadIdx.x;
    int c4 = (tid & 31) * 4;
    int wg = tid >> 5;               // 0..7

    float wreg[4][9];
    #pragma unroll
    for (int cc = 0; cc < 4; ++cc)
        #pragma unroll
        for (int p = 0; p < 9; ++p)
            wreg[cc][p] = dww[(c4 + cc) * 9 + p];
    float bia[4];
    #pragma unroll
    for (int cc = 0; cc < 4; ++cc) bia[cc] = dwb[c4 + cc];

    float s4[4] = {0,0,0,0}, q4[4] = {0,0,0,0};
    const float* ibase = inp + (size_t)(b << 12) * CDIM;

    for (int i = 0; i < 8; ++i) {
        int w = wg + i * 8;
        float acc[4] = {bia[0], bia[1], bia[2], bia[3]};
        #pragma unroll
        for (int ky = 0; ky < 3; ++ky) {
            int yy = h + ky - 1;
            if (yy < 0 || yy >= HS) continue;
            #pragma unroll
            for (int kx = 0; kx < 3; ++kx) {
                int xx = w + kx - 1;
                if (xx < 0 || xx >= WSZ) continue;
                float4 v = *(const float4*)(ibase + (size_t)(yy * 64 + xx) * CDIM + c4);
                int p = ky * 3 + kx;
                acc[0] += v.x * wreg[0][p];
                acc[1] += v.y * wreg[1][p];
                acc[2] += v.z * wreg[2][p];
                acc[3] += v.w * wreg[3][p];
            }
        }
        float4 o = {acc[0], acc[1], acc[2], acc[3]};
        *(float4*)(ydw + ((size_t)(b << 12) + h * 64 + w) * CDIM + c4) = o;
        #pragma unroll
        for (int cc = 0; cc < 4; ++cc) { s4[cc] += acc[cc]; q4[cc] += acc[cc] * acc[cc]; }
    }

    __shared__ float ls[8][128], lq[8][128];
    #pragma unroll
    for (int cc = 0; cc < 4; ++cc) { ls[wg][c4 + cc] = s4[cc]; lq[wg][c4 + cc] = q4[cc]; }
    __syncthreads();
    if (tid < 128) {
        float s = 0.f, q = 0.f;
        #pragma unroll
        for (int r = 0; r < 8; ++r) { s += ls[r][tid]; q += lq[r][tid]; }
        psum[blk * 128 + tid] = s;
        psq [blk * 128 + tid] = q;
    }
}

// ---------------------------------------------------------------------------
// K2: finalize BN stats -> scale/shift per channel.
// ---------------------------------------------------------------------------
__global__ __launch_bounds__(256) void k_bnstats(
    const float* __restrict__ psum, const float* __restrict__ psq,
    const float* __restrict__ gamma, const float* __restrict__ beta,
    float* __restrict__ sc, float* __restrict__ sh)
{
    int c = blockIdx.x;
    int t = threadIdx.x;
    float s = psum[t * 128 + c] + psum[(t + 256) * 128 + c];
    float q = psq [t * 128 + c] + psq [(t + 256) * 128 + c];
    __shared__ float rs[256], rq[256];
    rs[t] = s; rq[t] = q; __syncthreads();
    for (int off = 128; off > 0; off >>= 1) {
        if (t < off) { rs[t] += rs[t + off]; rq[t] += rq[t + off]; }
        __syncthreads();
    }
    if (t == 0) {
        float mean = rs[0] * (1.0f / 32768.0f);
        float var  = rq[0] * (1.0f / 32768.0f) - mean * mean;
        float scale = gamma[c] * rsqrtf(var + 1e-5f);
        sc[c] = scale;
        sh[c] = beta[c] - mean * scale;
    }
}

// ---------------------------------------------------------------------------
// K3: BN + exact GELU, ydw (fp32) -> x1 frag hi/lo. grid 2048, block 256.
// ---------------------------------------------------------------------------
__global__ __launch_bounds__(256) void k_bngelu(
    const float* __restrict__ ydw, const float* __restrict__ sc,
    const float* __restrict__ sh, unsigned short* __restrict__ dst)
{
    int idx = blockIdx.x * 256 + threadIdx.x;   // 32768*16
    int r = idx >> 4, k8 = (idx & 15) * 8;
    float t[8];
    *(float4*)(t)     = *(const float4*)(ydw + (size_t)r * 128 + k8);
    *(float4*)(t + 4) = *(const float4*)(ydw + (size_t)r * 128 + k8 + 4);
    float s[8], h[8];
    *(float4*)(s)     = *(const float4*)(sc + k8);
    *(float4*)(s + 4) = *(const float4*)(sc + k8 + 4);
    *(float4*)(h)     = *(const float4*)(sh + k8);
    *(float4*)(h + 4) = *(const float4*)(sh + k8 + 4);
    #pragma unroll
    for (int i = 0; i < 8; ++i) t[i] = gelu_exact(t[i] * s[i] + h[i]);
    uint4 hi, lo;
    pack8(t, hi, lo);
    int rt = r >> 4, kc = k8 >> 5, lp = (r & 15) + ((k8 & 31) >> 3) * 16;
    size_t base = ((size_t)rt * 4 + kc) * 1024 + lp * 8;
    *(uint4*)(dst + base)       = hi;
    *(uint4*)(dst + base + 512) = lo;
}

// ---------------------------------------------------------------------------
// K_wprep: weights W[N][K] fp32 -> fragment-ordered hi/lo bf16.
// ---------------------------------------------------------------------------
__global__ __launch_bounds__(64) void k_wprep(
    const float* __restrict__ w0, const float* __restrict__ w1,
    const float* __restrict__ w2, const float* __restrict__ w3,
    const float* __restrict__ w4, unsigned short* __restrict__ wb)
{
    int bid = blockIdx.x, lane = threadIdx.x;
    const float* W; int N, K, NT; unsigned short* out; int local;
    if (bid < 32)       { W = w0; N = 128; K = 128; NT = 8;  out = wb;          local = bid; }
    else if (bid < 68)  { W = w1; N = 144; K = 128; NT = 9;  out = wb + 32768;  local = bid - 32; }
    else if (bid < 88)  { W = w2; N = 72;  K = 128; NT = 5;  out = wb + 69632;  local = bid - 68; }
    else if (bid < 152) { W = w3; N = 256; K = 128; NT = 16; out = wb + 90112;  local = bid - 88; }
    else                { W = w4; N = 128; K = 256; NT = 8;  out = wb + 155648; local = bid - 152; }
    int KC = K / 32;
    int unit = KC * NT * 512;
    int kc = local / NT, t = local % NT;
    int n  = t * 16 + (lane & 15);
    int kb = kc * 32 + (lane >> 4) * 8;
    size_t base = ((size_t)local * 64 + lane) * 8;
    #pragma unroll
    for (int i = 0; i < 8; ++i) {
        float v = (n < N) ? W[(size_t)n * K + kb + i] : 0.f;
        __bf16 h = (__bf16)v;
        float  r = v - (float)h;
        __bf16 l = (__bf16)r;
        out[base + i]        = __builtin_bit_cast(unsigned short, h);
        out[unit + base + i] = __builtin_bit_cast(unsigned short, l);
    }
}

// ---------------------------------------------------------------------------
// Frag-stream MFMA GEMM, TLP+reuse version.
// grid: (rowtile_groups=256, n_chunks). block = 4 waves.
// wave = RT=2 rowtiles x NT_W n-tiles. hi/lo split -> 3 MFMAs, ~fp32 accuracy.
// MODE 0: fp32 row-major + bias. MODE 1: bias+GELU -> frag out.
// MODE 2: NCHW transposed store. MODE 3: padded [b][66][66][128] store.
// ---------------------------------------------------------------------------
template<int KDIM, int NT_TOT, int NT_W, int MODE, int NV>
__global__ __launch_bounds__(256) void k_fgemm(
    const unsigned short* __restrict__ AF, const unsigned short* __restrict__ WF,
    const float* __restrict__ bias, float* __restrict__ C, int ldc,
    unsigned short* __restrict__ OF)
{
    constexpr int KC = KDIM / 32;
    int tid = threadIdx.x;
    int lane = tid & 63, w = tid >> 6;
    int rt0 = blockIdx.x * 8 + w * 2;      // 2 rowtiles per wave
    int t0 = blockIdx.y * NT_W;            // n-tile chunk base

    f32x4 acc[2][NT_W];
    #pragma unroll
    for (int rt = 0; rt < 2; ++rt)
        #pragma unroll
        for (int t = 0; t < NT_W; ++t) acc[rt][t] = (f32x4){0.f, 0.f, 0.f, 0.f};

    const bf8_t* Ab0 = (const bf8_t*)AF + (size_t)rt0 * KC * 128 + lane;
    const bf8_t* Ab1 = Ab0 + KC * 128;
    const bf8_t* WHp = (const bf8_t*)WF + lane;
    const bf8_t* WLp = WHp + KC * NT_TOT * 64;

    #pragma unroll
    for (int kc = 0; kc < KC; ++kc) {
        bf8_t a0h = Ab0[kc * 128];
        bf8_t a0l = Ab0[kc * 128 + 64];
        bf8_t a1h = Ab1[kc * 128];
        bf8_t a1l = Ab1[kc * 128 + 64];
        #pragma unroll
        for (int t = 0; t < NT_W; ++t) {
            int tg = t0 + t;
            if (tg < NT_TOT) {
                bf8_t wh = WHp[(kc * NT_TOT + tg) * 64];
                bf8_t wl = WLp[(kc * NT_TOT + tg) * 64];
                if (MODE == 2) {
                    acc[0][t] = __builtin_amdgcn_mfma_f32_16x16x32_bf16(a0h, wh, acc[0][t], 0, 0, 0);
                    acc[0][t] = __builtin_amdgcn_mfma_f32_16x16x32_bf16(a0l, wh, acc[0][t], 0, 0, 0);
                    acc[0][t] = __builtin_amdgcn_mfma_f32_16x16x32_bf16(a0h, wl, acc[0][t], 0, 0, 0);
                    acc[1][t] = __builtin_amdgcn_mfma_f32_16x16x32_bf16(a1h, wh, acc[1][t], 0, 0, 0);
                    acc[1][t] = __builtin_amdgcn_mfma_f32_16x16x32_bf16(a1l, wh, acc[1][t], 0, 0, 0);
                    acc[1][t] = __builtin_amdgcn_mfma_f32_16x16x32_bf16(a1h, wl, acc[1][t], 0, 0, 0);
                } else {
                    acc[0][t] = __builtin_amdgcn_mfma_f32_16x16x32_bf16(wh, a0h, acc[0][t], 0, 0, 0);
                    acc[0][t] = __builtin_amdgcn_mfma_f32_16x16x32_bf16(wh, a0l, acc[0][t], 0, 0, 0);
                    acc[0][t] = __builtin_amdgcn_mfma_f32_16x16x32_bf16(wl, a0h, acc[0][t], 0, 0, 0);
                    acc[1][t] = __builtin_amdgcn_mfma_f32_16x16x32_bf16(wh, a1h, acc[1][t], 0, 0, 0);
                    acc[1][t] = __builtin_amdgcn_mfma_f32_16x16x32_bf16(wh, a1l, acc[1][t], 0, 0, 0);
                    acc[1][t] = __builtin_amdgcn_mfma_f32_16x16x32_bf16(wl, a1h, acc[1][t], 0, 0, 0);
                }
            }
        }
    }

    #pragma unroll
    for (int rt = 0; rt < 2; ++rt) {
        if (MODE == 0) {
            int m = (rt0 + rt) * 16 + (lane & 15);
            #pragma unroll
            for (int t = 0; t < NT_W; ++t) {
                int tg = t0 + t;
                int nb = tg * 16 + ((lane >> 4) << 2);
                if (tg < NT_TOT && nb + 4 <= NV) {
                    float4 bb = *(const float4*)(bias + nb);
                    f32x4 a = acc[rt][t];
                    float4 v = {a[0] + bb.x, a[1] + bb.y, a[2] + bb.z, a[3] + bb.w};
                    *(float4*)(C + (size_t)m * ldc + nb) = v;
                }
            }
        } else if (MODE == 1) {
            int m = (rt0 + rt) * 16 + (lane & 15);
            #pragma unroll
            for (int t = 0; t < NT_W; ++t) {
                int tg = t0 + t;
                if (tg < NT_TOT) {
                    int nb = tg * 16 + ((lane >> 4) << 2);
                    float4 bb = *(const float4*)(bias + nb);
                    f32x4 a = acc[rt][t];
                    float v[4];
                    v[0] = gelu_exact(a[0] + bb.x); v[1] = gelu_exact(a[1] + bb.y);
                    v[2] = gelu_exact(a[2] + bb.z); v[3] = gelu_exact(a[3] + bb.w);
                    unsigned hh[4], ll[4];
                    #pragma unroll
                    for (int i = 0; i < 4; ++i) hilo(v[i], hh[i], ll[i]);
                    uint2 hi = make_uint2(hh[0] | (hh[1] << 16), hh[2] | (hh[3] << 16));
                    uint2 lo = make_uint2(ll[0] | (ll[1] << 16), ll[2] | (ll[3] << 16));
                    int kco = nb >> 5, lp = (m & 15) + ((nb & 31) >> 3) * 16;
                    size_t fb = ((size_t)(rt0 + rt) * (NV / 32) + kco) * 1024 + lp * 8 + (nb & 7);
                    *(uint2*)(OF + fb)       = hi;
                    *(uint2*)(OF + fb + 512) = lo;
                }
            }
        } else if (MODE == 3) {
            int m = (rt0 + rt) * 16 + (lane & 15);
            int bb_ = m >> 12, hwm = m & 4095;
            size_t rowb = (((size_t)bb_ * 66 + (hwm >> 6) + 1) * 66 + (hwm & 63) + 1) * 128;
            #pragma unroll
            for (int t = 0; t < NT_W; ++t) {
                int tg = t0 + t;
                int nb = tg * 16 + ((lane >> 4) << 2);
                if (tg < NT_TOT) {
                    float4 bb = *(const float4*)(bias + nb);
                    f32x4 a = acc[rt][t];
                    float4 v = {a[0] + bb.x, a[1] + bb.y, a[2] + bb.z, a[3] + bb.w};
                    *(float4*)(C + rowb + nb) = v;
                }
            }
        } else {
            int m4 = (rt0 + rt) * 16 + ((lane >> 4) << 2);
            int b = m4 >> 12, hw = m4 & 4095;
            #pragma unroll
            for (int t = 0; t < NT_W; ++t) {
                int tg = t0 + t;
                if (tg < NT_TOT) {
                    int n = tg * 16 + (lane & 15);
                    float bb = bias[n];
                    f32x4 a = acc[rt][t];
                    float4 v = {a[0] + bb, a[1] + bb, a[2] + bb, a[3] + bb};
                    *(float4*)(C + (((size_t)(b * 128 + n)) << 12) + hw) = v;
                }
            }
        }
    }
}

// ---------------------------------------------------------------------------
// K6: DCNv3 core v2. thread = (pos, g), 16 channels. grid 1024, block 256.
// Unconditional bilinear gathers from zero-padded xpad (clamp == pad zeros).
// Softmax computed once per (pos,g). Output packed as fc1 A-frags (hi/lo).
// ---------------------------------------------------------------------------
__global__ __launch_bounds__(256) void k_dcn(
    const float* __restrict__ xpad, const float* __restrict__ offs,
    const float* __restrict__ msk, unsigned short* __restrict__ dcnf)
{
    int u = blockIdx.x * 256 + threadIdx.x;  // 32768*8
    int g = u & 7;
    int pos = u >> 3;
    int b = pos >> 12, hw = pos & 4095, h = hw >> 6, w = hw & 63;

    const float* ml = msk + (size_t)pos * 72 + g * 9;
    float e[9];
    float mx = -1e30f;
    #pragma unroll
    for (int p = 0; p < 9; ++p) { e[p] = ml[p]; mx = fmaxf(mx, e[p]); }
    float ssum = 0.f;
    #pragma unroll
    for (int p = 0; p < 9; ++p) { e[p] = __expf(e[p] - mx); ssum += e[p]; }
    float inv = 1.0f / ssum;

    const float2* ob2 = (const float2*)(offs + (size_t)pos * 144 + g * 18);
    const float* xb = xpad + (size_t)b * 557568 + g * 16;   // 66*66*128 per batch

    f32x4 acc[4];
    #pragma unroll
    for (int cc = 0; cc < 4; ++cc) acc[cc] = (f32x4){0.f, 0.f, 0.f, 0.f};

    #pragma unroll
    for (int p = 0; p < 9; ++p) {
        float2 d = ob2[p];
        float px = (float)(w + (p % 3)) + d.x;   // padded-grid coords
        float py = (float)(h + (p / 3)) + d.y;
        float x0f = floorf(px), y0f = floorf(py);
        float wx = px - x0f, wy = py - y0f;
        int ix = (int)x0f, iy = (int)y0f;
        int ix0 = max(min(ix, 65), 0),     ix1 = max(min(ix + 1, 65), 0);
        int iy0 = max(min(iy, 65), 0),     iy1 = max(min(iy + 1, 65), 0);
        int r0 = iy0 * 66, r1 = iy1 * 66;
        const float* p00 = xb + (r0 + ix0) * 128;
        const float* p01 = xb + (r0 + ix1) * 128;
        const float* p10 = xb + (r1 + ix0) * 128;
        const float* p11 = xb + (r1 + ix1) * 128;

        float mp  = e[p] * inv;
        float w11 = wy * wx * mp;
        float w10 = wy * mp - w11;
        float w01 = wx * mp - w11;
        float w00 = mp - w01 - w10 - w11;

        #pragma unroll
        for (int cc = 0; cc < 4; ++cc) {
            float4 s00 = *(const float4*)(p00 + cc * 4);
            float4 s01 = *(const float4*)(p01 + cc * 4);
            float4 s10 = *(const float4*)(p10 + cc * 4);
            float4 s11 = *(const float4*)(p11 + cc * 4);
            acc[cc][0] += s00.x * w00 + s01.x * w01 + s10.x * w10 + s11.x * w11;
            acc[cc][1] += s00.y * w00 + s01.y * w01 + s10.y * w10 + s11.y * w11;
            acc[cc][2] += s00.z * w00 + s01.z * w01 + s10.z * w10 + s11.z * w11;
            acc[cc][3] += s00.w * w00 + s01.w * w01 + s10.w * w10 + s11.w * w11;
        }
    }

    // pack 16 channels (ch = g*16 .. +15) as two 8-element frag groups
    int ch = g * 16;
    int rt = pos >> 4, kc = ch >> 5;                       // kc = g>>1
    int lp0 = (pos & 15) + ((ch & 31) >> 3) * 16;          // + (g&1)*32
    size_t fb = ((size_t)rt * 4 + kc) * 1024 + (size_t)lp0 * 8;

    float va[8], vb[8];
    #pragma unroll
    for (int i = 0; i < 4; ++i) {
        va[i] = acc[0][i]; va[4 + i] = acc[1][i];
        vb[i] = acc[2][i]; vb[4 + i] = acc[3][i];
    }
    uint4 hiA, loA, hiB, loB;
    pack8(va, hiA, loA);
    pack8(vb, hiB, loB);
    *(uint4*)(dcnf + fb)             = hiA;
    *(uint4*)(dcnf + fb + 512)       = loA;
    *(uint4*)(dcnf + fb + 128)       = hiB;   // lp0+16 -> +16*8
    *(uint4*)(dcnf + fb + 128 + 512) = loB;
}

// ---------------------------------------------------------------------------
extern "C" void kernel_launch(void* const* d_in, const int* in_sizes, int n_in,
                              void* d_out, int out_size, void* d_ws, size_t ws_size,
                              hipStream_t stream)
{
    const float* inp   = (const float*)d_in[0];
    const float* wproj = (const float*)d_in[1];
    const float* bproj = (const float*)d_in[2];
    const float* dww   = (const float*)d_in[3];
    const float* dwb   = (const float*)d_in[4];
    const float* gamma = (const float*)d_in[5];
    const float* beta  = (const float*)d_in[6];
    const float* woff  = (const float*)d_in[7];
    const float* boff  = (const float*)d_in[8];
    const float* wmask = (const float*)d_in[9];
    const float* bmask = (const float*)d_in[10];
    const float* wfc1  = (const float*)d_in[11];
    const float* bfc1  = (const float*)d_in[12];
    const float* wfc2  = (const float*)d_in[13];
    const float* bfc2  = (const float*)d_in[14];
    float* out = (float*)d_out;
    float* ws  = (float*)d_ws;

    // Region P [0, 9179136): xpad + offs; later hdnf (fc1 out frags)
    float* xpad = ws;                                    // 4,460,544 f [proj..dcn]
    float* offs = ws + 4460544;                          // 4,718,592 f [off..dcn]
    unsigned short* hdnf = (unsigned short*)ws;          // 16,777,216 ush [fc1..fc2]
    // Region A [9179136, 17567744): time-shared
    float* ydw            = ws + 9179136;                // 4,194,304 f [dwconv..bngelu]
    unsigned short* inpf  = (unsigned short*)(ws + 9179136);   // [aprep..proj]
    unsigned short* dcnf  = (unsigned short*)(ws + 9179136);   // [dcn..fc1]
    unsigned short* x1f   = (unsigned short*)(ws + 13373440);  // [bngelu..mask]
    // Rest
    float* msk  = ws + 17567744;                         // 2,359,296 f
    float* psum = ws + 19927040;                         // 65,536 f
    float* psq  = ws + 19992576;                         // 65,536 f
    float* scs  = ws + 20058112;                         // 128 f
    float* shs  = ws + 20058240;                         // 128 f
    unsigned short* wfr = (unsigned short*)(ws + 20058368);  // 221,184 ush

    unsigned short* wproj_f = wfr;
    unsigned short* woff_f  = wfr + 32768;
    unsigned short* wmask_f = wfr + 69632;
    unsigned short* wfc1_f  = wfr + 90112;
    unsigned short* wfc2_f  = wfr + 155648;

    k_wprep<<<216, 64, 0, stream>>>(wproj, woff, wmask, wfc1, wfc2, wfr);
    k_aprep<<<2048, 256, 0, stream>>>(inp, inpf);
    k_border<<<260, 256, 0, stream>>>(xpad);
    k_fgemm<128,  8, 2, 3, 128><<<dim3(256, 4), 256, 0, stream>>>(inpf, wproj_f, bproj, xpad, 0, nullptr);
    k_dwconv<<<512, 256, 0, stream>>>(inp, dww, dwb, ydw, psum, psq);
    k_bnstats<<<128, 256, 0, stream>>>(psum, psq, gamma, beta, scs, shs);
    k_bngelu<<<2048, 256, 0, stream>>>(ydw, scs, shs, x1f);
    k_fgemm<128,  9, 3, 0, 144><<<dim3(256, 3), 256, 0, stream>>>(x1f, woff_f, boff, offs, 144, nullptr);
    k_fgemm<128,  5, 3, 0,  72><<<dim3(256, 2), 256, 0, stream>>>(x1f, wmask_f, bmask, msk, 72, nullptr);
    k_dcn<<<1024, 256, 0, stream>>>(xpad, offs, msk, dcnf);
    k_fgemm<128, 16, 4, 1, 256><<<dim3(256, 4), 256, 0, stream>>>(dcnf, wfc1_f, bfc1, nullptr, 0, hdnf);
    k_fgemm<256,  8, 2, 2, 128><<<dim3(256, 4), 256, 0, stream>>>(hdnf, wfc2_f, bfc2, out, 0, nullptr);
}

// Round 6
// 144.264 us; speedup vs baseline: 1.1755x; 1.1755x over previous
//
#include <hip/hip_runtime.h>
#include <math.h>

#define NPOS  32768      // B*H*W
#define CDIM  128
#define HS    64
#define WSZ   64

typedef __bf16 bf8_t  __attribute__((ext_vector_type(8)));
typedef float  f32x4  __attribute__((ext_vector_type(4)));

__device__ __forceinline__ float gelu_exact(float x) {
    return 0.5f * x * (1.0f + erff(x * 0.70710678118654752f));
}

__device__ __forceinline__ void hilo(float v, unsigned& h, unsigned& l) {
    __bf16 hb = (__bf16)v;
    h = (unsigned)__builtin_bit_cast(unsigned short, hb);
    __bf16 lb = (__bf16)(v - (float)hb);
    l = (unsigned)__builtin_bit_cast(unsigned short, lb);
}

__device__ __forceinline__ void pack8(const float* v, uint4& hi, uint4& lo) {
    unsigned hh[8], ll[8];
    #pragma unroll
    for (int i = 0; i < 8; ++i) hilo(v[i], hh[i], ll[i]);
    hi = make_uint4(hh[0] | (hh[1] << 16), hh[2] | (hh[3] << 16),
                    hh[4] | (hh[5] << 16), hh[6] | (hh[7] << 16));
    lo = make_uint4(ll[0] | (ll[1] << 16), ll[2] | (ll[3] << 16),
                    ll[4] | (ll[5] << 16), ll[6] | (ll[7] << 16));
}

// ---------------------------------------------------------------------------
// A-frag layout (K=KC*32): ushort buffer; block(rt,kc) at (rt*KC+kc)*1024,
// hi elem: lane*8 + i  (lane = (row%16) + ((k%32)/8)*16, i = k%8), lo at +512.
// ---------------------------------------------------------------------------

// K_aprep: fp32 row-major [32768][128] -> frag hi/lo. grid 2048, block 256.
__global__ __launch_bounds__(256) void k_aprep(
    const float* __restrict__ src, unsigned short* __restrict__ dst)
{
    int idx = blockIdx.x * 256 + threadIdx.x;   // 32768*16
    int r = idx >> 4, k8 = (idx & 15) * 8;
    float t[8];
    *(float4*)(t)     = *(const float4*)(src + (size_t)r * 128 + k8);
    *(float4*)(t + 4) = *(const float4*)(src + (size_t)r * 128 + k8 + 4);
    uint4 hi, lo;
    pack8(t, hi, lo);
    int rt = r >> 4, kc = k8 >> 5, lp = (r & 15) + ((k8 & 31) >> 3) * 16;
    size_t base = ((size_t)rt * 4 + kc) * 1024 + lp * 8;
    *(uint4*)(dst + base)       = hi;
    *(uint4*)(dst + base + 512) = lo;
}

// K_border: zero the 1-px ring of xpad[b][66][66][128]. grid 260, block 256.
__global__ __launch_bounds__(256) void k_border(float* __restrict__ xpad)
{
    int idx = blockIdx.x * 256 + threadIdx.x;  // 8*260*32 = 66560
    int c4 = (idx & 31) * 4;
    int cell = idx >> 5;                       // 0..2079
    int b = cell / 260, r = cell % 260;
    int h, w;
    if (r < 66)       { h = 0;  w = r; }
    else if (r < 132) { h = 65; w = r - 66; }
    else { int rr = r - 132; h = 1 + (rr >> 1); w = (rr & 1) * 65; }
    size_t o = (((size_t)b * 66 + h) * 66 + w) * 128 + c4;
    *(float4*)(xpad + o) = make_float4(0.f, 0.f, 0.f, 0.f);
}

// ---------------------------------------------------------------------------
// K1: depthwise 3x3 conv (NHWC) + per-block partial BN sums
// ---------------------------------------------------------------------------
__global__ __launch_bounds__(256) void k_dwconv(
    const float* __restrict__ inp, const float* __restrict__ dww,
    const float* __restrict__ dwb, float* __restrict__ ydw,
    float* __restrict__ psum, float* __restrict__ psq)
{
    int blk = blockIdx.x;            // b*64 + h
    int b = blk >> 6, h = blk & 63;
    int tid = threadIdx.x;
    int c4 = (tid & 31) * 4;
    int wg = tid >> 5;               // 0..7

    float wreg[4][9];
    #pragma unroll
    for (int cc = 0; cc < 4; ++cc)
        #pragma unroll
        for (int p = 0; p < 9; ++p)
            wreg[cc][p] = dww[(c4 + cc) * 9 + p];
    float bia[4];
    #pragma unroll
    for (int cc = 0; cc < 4; ++cc) bia[cc] = dwb[c4 + cc];

    float s4[4] = {0,0,0,0}, q4[4] = {0,0,0,0};
    const float* ibase = inp + (size_t)(b << 12) * CDIM;

    for (int i = 0; i < 8; ++i) {
        int w = wg + i * 8;
        float acc[4] = {bia[0], bia[1], bia[2], bia[3]};
        #pragma unroll
        for (int ky = 0; ky < 3; ++ky) {
            int yy = h + ky - 1;
            if (yy < 0 || yy >= HS) continue;
            #pragma unroll
            for (int kx = 0; kx < 3; ++kx) {
                int xx = w + kx - 1;
                if (xx < 0 || xx >= WSZ) continue;
                float4 v = *(const float4*)(ibase + (size_t)(yy * 64 + xx) * CDIM + c4);
                int p = ky * 3 + kx;
                acc[0] += v.x * wreg[0][p];
                acc[1] += v.y * wreg[1][p];
                acc[2] += v.z * wreg[2][p];
                acc[3] += v.w * wreg[3][p];
            }
        }
        float4 o = {acc[0], acc[1], acc[2], acc[3]};
        *(float4*)(ydw + ((size_t)(b << 12) + h * 64 + w) * CDIM + c4) = o;
        #pragma unroll
        for (int cc = 0; cc < 4; ++cc) { s4[cc] += acc[cc]; q4[cc] += acc[cc] * acc[cc]; }
    }

    __shared__ float ls[8][128], lq[8][128];
    #pragma unroll
    for (int cc = 0; cc < 4; ++cc) { ls[wg][c4 + cc] = s4[cc]; lq[wg][c4 + cc] = q4[cc]; }
    __syncthreads();
    if (tid < 128) {
        float s = 0.f, q = 0.f;
        #pragma unroll
        for (int r = 0; r < 8; ++r) { s += ls[r][tid]; q += lq[r][tid]; }
        psum[blk * 128 + tid] = s;
        psq [blk * 128 + tid] = q;
    }
}

// ---------------------------------------------------------------------------
// K2: finalize BN stats -> scale/shift per channel.
// ---------------------------------------------------------------------------
__global__ __launch_bounds__(256) void k_bnstats(
    const float* __restrict__ psum, const float* __restrict__ psq,
    const float* __restrict__ gamma, const float* __restrict__ beta,
    float* __restrict__ sc, float* __restrict__ sh)
{
    int c = blockIdx.x;
    int t = threadIdx.x;
    float s = psum[t * 128 + c] + psum[(t + 256) * 128 + c];
    float q = psq [t * 128 + c] + psq [(t + 256) * 128 + c];
    __shared__ float rs[256], rq[256];
    rs[t] = s; rq[t] = q; __syncthreads();
    for (int off = 128; off > 0; off >>= 1) {
        if (t < off) { rs[t] += rs[t + off]; rq[t] += rq[t + off]; }
        __syncthreads();
    }
    if (t == 0) {
        float mean = rs[0] * (1.0f / 32768.0f);
        float var  = rq[0] * (1.0f / 32768.0f) - mean * mean;
        float scale = gamma[c] * rsqrtf(var + 1e-5f);
        sc[c] = scale;
        sh[c] = beta[c] - mean * scale;
    }
}

// ---------------------------------------------------------------------------
// K3: BN + exact GELU, ydw (fp32) -> x1 frag hi/lo. grid 2048, block 256.
// ---------------------------------------------------------------------------
__global__ __launch_bounds__(256) void k_bngelu(
    const float* __restrict__ ydw, const float* __restrict__ sc,
    const float* __restrict__ sh, unsigned short* __restrict__ dst)
{
    int idx = blockIdx.x * 256 + threadIdx.x;   // 32768*16
    int r = idx >> 4, k8 = (idx & 15) * 8;
    float t[8];
    *(float4*)(t)     = *(const float4*)(ydw + (size_t)r * 128 + k8);
    *(float4*)(t + 4) = *(const float4*)(ydw + (size_t)r * 128 + k8 + 4);
    float s[8], h[8];
    *(float4*)(s)     = *(const float4*)(sc + k8);
    *(float4*)(s + 4) = *(const float4*)(sc + k8 + 4);
    *(float4*)(h)     = *(const float4*)(sh + k8);
    *(float4*)(h + 4) = *(const float4*)(sh + k8 + 4);
    #pragma unroll
    for (int i = 0; i < 8; ++i) t[i] = gelu_exact(t[i] * s[i] + h[i]);
    uint4 hi, lo;
    pack8(t, hi, lo);
    int rt = r >> 4, kc = k8 >> 5, lp = (r & 15) + ((k8 & 31) >> 3) * 16;
    size_t base = ((size_t)rt * 4 + kc) * 1024 + lp * 8;
    *(uint4*)(dst + base)       = hi;
    *(uint4*)(dst + base + 512) = lo;
}

// ---------------------------------------------------------------------------
// K_wprep: weights W[N][K] fp32 -> fragment-ordered hi/lo bf16.
// ---------------------------------------------------------------------------
__global__ __launch_bounds__(64) void k_wprep(
    const float* __restrict__ w0, const float* __restrict__ w1,
    const float* __restrict__ w2, const float* __restrict__ w3,
    const float* __restrict__ w4, unsigned short* __restrict__ wb)
{
    int bid = blockIdx.x, lane = threadIdx.x;
    const float* W; int N, K, NT; unsigned short* out; int local;
    if (bid < 32)       { W = w0; N = 128; K = 128; NT = 8;  out = wb;          local = bid; }
    else if (bid < 68)  { W = w1; N = 144; K = 128; NT = 9;  out = wb + 32768;  local = bid - 32; }
    else if (bid < 88)  { W = w2; N = 72;  K = 128; NT = 5;  out = wb + 69632;  local = bid - 68; }
    else if (bid < 152) { W = w3; N = 256; K = 128; NT = 16; out = wb + 90112;  local = bid - 88; }
    else                { W = w4; N = 128; K = 256; NT = 8;  out = wb + 155648; local = bid - 152; }
    int KC = K / 32;
    int unit = KC * NT * 512;
    int kc = local / NT, t = local % NT;
    int n  = t * 16 + (lane & 15);
    int kb = kc * 32 + (lane >> 4) * 8;
    size_t base = ((size_t)local * 64 + lane) * 8;
    #pragma unroll
    for (int i = 0; i < 8; ++i) {
        float v = (n < N) ? W[(size_t)n * K + kb + i] : 0.f;
        __bf16 h = (__bf16)v;
        float  r = v - (float)h;
        __bf16 l = (__bf16)r;
        out[base + i]        = __builtin_bit_cast(unsigned short, h);
        out[unit + base + i] = __builtin_bit_cast(unsigned short, l);
    }
}

// ---------------------------------------------------------------------------
// Frag-stream MFMA GEMM, TLP+reuse version.
// grid: (rowtile_groups=256, n_chunks). block = 4 waves.
// wave = RT=2 rowtiles x NT_W n-tiles. hi/lo split -> 3 MFMAs, ~fp32 accuracy.
// MODE 0: fp32 row-major + bias. MODE 1: bias+GELU -> frag out.
// MODE 2: NCHW transposed store. MODE 3: padded [b][66][66][128] store.
// ---------------------------------------------------------------------------
template<int KDIM, int NT_TOT, int NT_W, int MODE, int NV>
__global__ __launch_bounds__(256) void k_fgemm(
    const unsigned short* __restrict__ AF, const unsigned short* __restrict__ WF,
    const float* __restrict__ bias, float* __restrict__ C, int ldc,
    unsigned short* __restrict__ OF)
{
    constexpr int KC = KDIM / 32;
    int tid = threadIdx.x;
    int lane = tid & 63, w = tid >> 6;
    int rt0 = blockIdx.x * 8 + w * 2;      // 2 rowtiles per wave
    int t0 = blockIdx.y * NT_W;            // n-tile chunk base

    f32x4 acc[2][NT_W];
    #pragma unroll
    for (int rt = 0; rt < 2; ++rt)
        #pragma unroll
        for (int t = 0; t < NT_W; ++t) acc[rt][t] = (f32x4){0.f, 0.f, 0.f, 0.f};

    const bf8_t* Ab0 = (const bf8_t*)AF + (size_t)rt0 * KC * 128 + lane;
    const bf8_t* Ab1 = Ab0 + KC * 128;
    const bf8_t* WHp = (const bf8_t*)WF + lane;
    const bf8_t* WLp = WHp + KC * NT_TOT * 64;

    #pragma unroll
    for (int kc = 0; kc < KC; ++kc) {
        bf8_t a0h = Ab0[kc * 128];
        bf8_t a0l = Ab0[kc * 128 + 64];
        bf8_t a1h = Ab1[kc * 128];
        bf8_t a1l = Ab1[kc * 128 + 64];
        #pragma unroll
        for (int t = 0; t < NT_W; ++t) {
            int tg = t0 + t;
            if (tg < NT_TOT) {
                bf8_t wh = WHp[(kc * NT_TOT + tg) * 64];
                bf8_t wl = WLp[(kc * NT_TOT + tg) * 64];
                if (MODE == 2) {
                    acc[0][t] = __builtin_amdgcn_mfma_f32_16x16x32_bf16(a0h, wh, acc[0][t], 0, 0, 0);
                    acc[0][t] = __builtin_amdgcn_mfma_f32_16x16x32_bf16(a0l, wh, acc[0][t], 0, 0, 0);
                    acc[0][t] = __builtin_amdgcn_mfma_f32_16x16x32_bf16(a0h, wl, acc[0][t], 0, 0, 0);
                    acc[1][t] = __builtin_amdgcn_mfma_f32_16x16x32_bf16(a1h, wh, acc[1][t], 0, 0, 0);
                    acc[1][t] = __builtin_amdgcn_mfma_f32_16x16x32_bf16(a1l, wh, acc[1][t], 0, 0, 0);
                    acc[1][t] = __builtin_amdgcn_mfma_f32_16x16x32_bf16(a1h, wl, acc[1][t], 0, 0, 0);
                } else {
                    acc[0][t] = __builtin_amdgcn_mfma_f32_16x16x32_bf16(wh, a0h, acc[0][t], 0, 0, 0);
                    acc[0][t] = __builtin_amdgcn_mfma_f32_16x16x32_bf16(wh, a0l, acc[0][t], 0, 0, 0);
                    acc[0][t] = __builtin_amdgcn_mfma_f32_16x16x32_bf16(wl, a0h, acc[0][t], 0, 0, 0);
                    acc[1][t] = __builtin_amdgcn_mfma_f32_16x16x32_bf16(wh, a1h, acc[1][t], 0, 0, 0);
                    acc[1][t] = __builtin_amdgcn_mfma_f32_16x16x32_bf16(wh, a1l, acc[1][t], 0, 0, 0);
                    acc[1][t] = __builtin_amdgcn_mfma_f32_16x16x32_bf16(wl, a1h, acc[1][t], 0, 0, 0);
                }
            }
        }
    }

    #pragma unroll
    for (int rt = 0; rt < 2; ++rt) {
        if (MODE == 0) {
            int m = (rt0 + rt) * 16 + (lane & 15);
            #pragma unroll
            for (int t = 0; t < NT_W; ++t) {
                int tg = t0 + t;
                int nb = tg * 16 + ((lane >> 4) << 2);
                if (tg < NT_TOT && nb + 4 <= NV) {
                    float4 bb = *(const float4*)(bias + nb);
                    f32x4 a = acc[rt][t];
                    float4 v = {a[0] + bb.x, a[1] + bb.y, a[2] + bb.z, a[3] + bb.w};
                    *(float4*)(C + (size_t)m * ldc + nb) = v;
                }
            }
        } else if (MODE == 1) {
            int m = (rt0 + rt) * 16 + (lane & 15);
            #pragma unroll
            for (int t = 0; t < NT_W; ++t) {
                int tg = t0 + t;
                if (tg < NT_TOT) {
                    int nb = tg * 16 + ((lane >> 4) << 2);
                    float4 bb = *(const float4*)(bias + nb);
                    f32x4 a = acc[rt][t];
                    float v[4];
                    v[0] = gelu_exact(a[0] + bb.x); v[1] = gelu_exact(a[1] + bb.y);
                    v[2] = gelu_exact(a[2] + bb.z); v[3] = gelu_exact(a[3] + bb.w);
                    unsigned hh[4], ll[4];
                    #pragma unroll
                    for (int i = 0; i < 4; ++i) hilo(v[i], hh[i], ll[i]);
                    uint2 hi = make_uint2(hh[0] | (hh[1] << 16), hh[2] | (hh[3] << 16));
                    uint2 lo = make_uint2(ll[0] | (ll[1] << 16), ll[2] | (ll[3] << 16));
                    int kco = nb >> 5, lp = (m & 15) + ((nb & 31) >> 3) * 16;
                    size_t fb = ((size_t)(rt0 + rt) * (NV / 32) + kco) * 1024 + lp * 8 + (nb & 7);
                    *(uint2*)(OF + fb)       = hi;
                    *(uint2*)(OF + fb + 512) = lo;
                }
            }
        } else if (MODE == 3) {
            int m = (rt0 + rt) * 16 + (lane & 15);
            int bb_ = m >> 12, hwm = m & 4095;
            size_t rowb = (((size_t)bb_ * 66 + (hwm >> 6) + 1) * 66 + (hwm & 63) + 1) * 128;
            #pragma unroll
            for (int t = 0; t < NT_W; ++t) {
                int tg = t0 + t;
                int nb = tg * 16 + ((lane >> 4) << 2);
                if (tg < NT_TOT) {
                    float4 bb = *(const float4*)(bias + nb);
                    f32x4 a = acc[rt][t];
                    float4 v = {a[0] + bb.x, a[1] + bb.y, a[2] + bb.z, a[3] + bb.w};
                    *(float4*)(C + rowb + nb) = v;
                }
            }
        } else {
            int m4 = (rt0 + rt) * 16 + ((lane >> 4) << 2);
            int b = m4 >> 12, hw = m4 & 4095;
            #pragma unroll
            for (int t = 0; t < NT_W; ++t) {
                int tg = t0 + t;
                if (tg < NT_TOT) {
                    int n = tg * 16 + (lane & 15);
                    float bb = bias[n];
                    f32x4 a = acc[rt][t];
                    float4 v = {a[0] + bb, a[1] + bb, a[2] + bb, a[3] + bb};
                    *(float4*)(C + (((size_t)(b * 128 + n)) << 12) + hw) = v;
                }
            }
        }
    }
}

// ---------------------------------------------------------------------------
// K6: DCNv3 core v3. thread = (pos, g, quarter), 4 channels. grid 4096.
// Max parallelism (1M threads, low VGPR) + unconditional clamped gathers
// from zero-padded xpad. Softmax redundant x4 (VALU is idle anyway).
// Output packed directly as fc1 A-frags (hi/lo).
// ---------------------------------------------------------------------------
__global__ __launch_bounds__(256) void k_dcn(
    const float* __restrict__ xpad, const float* __restrict__ offs,
    const float* __restrict__ msk, unsigned short* __restrict__ dcnf)
{
    int u = blockIdx.x * 256 + threadIdx.x;  // 32768*8*4
    int q = u & 3;
    int pg = u >> 2;
    int g = pg & 7;
    int pos = pg >> 3;
    int b = pos >> 12, hw = pos & 4095, h = hw >> 6, w = hw & 63;

    const float* ml = msk + (size_t)pos * 72 + g * 9;
    float e[9];
    float mx = -1e30f;
    #pragma unroll
    for (int p = 0; p < 9; ++p) { e[p] = ml[p]; mx = fmaxf(mx, e[p]); }
    float ssum = 0.f;
    #pragma unroll
    for (int p = 0; p < 9; ++p) { e[p] = __expf(e[p] - mx); ssum += e[p]; }
    float inv = 1.0f / ssum;

    const float2* ob2 = (const float2*)(offs + (size_t)pos * 144 + g * 18);
    int ch = g * 16 + q * 4;
    const float* xb = xpad + (size_t)b * 557568 + ch;   // 66*66*128 per batch

    f32x4 acc = (f32x4){0.f, 0.f, 0.f, 0.f};

    #pragma unroll
    for (int p = 0; p < 9; ++p) {
        float2 d = ob2[p];
        float px = (float)(w + (p % 3)) + d.x;   // padded-grid coords
        float py = (float)(h + (p / 3)) + d.y;
        float x0f = floorf(px), y0f = floorf(py);
        float wx = px - x0f, wy = py - y0f;
        int ix = (int)x0f, iy = (int)y0f;
        int ix0 = max(min(ix, 65), 0),     ix1 = max(min(ix + 1, 65), 0);
        int iy0 = max(min(iy, 65), 0),     iy1 = max(min(iy + 1, 65), 0);
        int r0 = iy0 * 66, r1 = iy1 * 66;

        float mp  = e[p] * inv;
        float w11 = wy * wx * mp;
        float w10 = wy * mp - w11;
        float w01 = wx * mp - w11;
        float w00 = mp - w01 - w10 - w11;

        float4 s00 = *(const float4*)(xb + (size_t)(r0 + ix0) * 128);
        float4 s01 = *(const float4*)(xb + (size_t)(r0 + ix1) * 128);
        float4 s10 = *(const float4*)(xb + (size_t)(r1 + ix0) * 128);
        float4 s11 = *(const float4*)(xb + (size_t)(r1 + ix1) * 128);

        acc[0] += s00.x * w00 + s01.x * w01 + s10.x * w10 + s11.x * w11;
        acc[1] += s00.y * w00 + s01.y * w01 + s10.y * w10 + s11.y * w11;
        acc[2] += s00.z * w00 + s01.z * w01 + s10.z * w10 + s11.z * w11;
        acc[3] += s00.w * w00 + s01.w * w01 + s10.w * w10 + s11.w * w11;
    }

    float v[4] = {acc[0], acc[1], acc[2], acc[3]};
    unsigned hh[4], ll[4];
    #pragma unroll
    for (int i = 0; i < 4; ++i) hilo(v[i], hh[i], ll[i]);
    uint2 hi = make_uint2(hh[0] | (hh[1] << 16), hh[2] | (hh[3] << 16));
    uint2 lo = make_uint2(ll[0] | (ll[1] << 16), ll[2] | (ll[3] << 16));
    int rt = pos >> 4, kcf = ch >> 5, lp = (pos & 15) + ((ch & 31) >> 3) * 16;
    size_t fb = ((size_t)rt * 4 + kcf) * 1024 + lp * 8 + (ch & 7);
    *(uint2*)(dcnf + fb)       = hi;
    *(uint2*)(dcnf + fb + 512) = lo;
}

// ---------------------------------------------------------------------------
extern "C" void kernel_launch(void* const* d_in, const int* in_sizes, int n_in,
                              void* d_out, int out_size, void* d_ws, size_t ws_size,
                              hipStream_t stream)
{
    const float* inp   = (const float*)d_in[0];
    const float* wproj = (const float*)d_in[1];
    const float* bproj = (const float*)d_in[2];
    const float* dww   = (const float*)d_in[3];
    const float* dwb   = (const float*)d_in[4];
    const float* gamma = (const float*)d_in[5];
    const float* beta  = (const float*)d_in[6];
    const float* woff  = (const float*)d_in[7];
    const float* boff  = (const float*)d_in[8];
    const float* wmask = (const float*)d_in[9];
    const float* bmask = (const float*)d_in[10];
    const float* wfc1  = (const float*)d_in[11];
    const float* bfc1  = (const float*)d_in[12];
    const float* wfc2  = (const float*)d_in[13];
    const float* bfc2  = (const float*)d_in[14];
    float* out = (float*)d_out;
    float* ws  = (float*)d_ws;

    // Region P [0, 9179136): xpad + offs; later hdnf (fc1 out frags)
    float* xpad = ws;                                    // 4,460,544 f [proj..dcn]
    float* offs = ws + 4460544;                          // 4,718,592 f [off..dcn]
    unsigned short* hdnf = (unsigned short*)ws;          // 16,777,216 ush [fc1..fc2]
    // Region A [9179136, 17567744): time-shared
    float* ydw            = ws + 9179136;                // 4,194,304 f [dwconv..bngelu]
    unsigned short* inpf  = (unsigned short*)(ws + 9179136);   // [aprep..proj]
    unsigned short* dcnf  = (unsigned short*)(ws + 9179136);   // [dcn..fc1]
    unsigned short* x1f   = (unsigned short*)(ws + 13373440);  // [bngelu..mask]
    // Rest
    float* msk  = ws + 17567744;                         // 2,359,296 f
    float* psum = ws + 19927040;                         // 65,536 f
    float* psq  = ws + 19992576;                         // 65,536 f
    float* scs  = ws + 20058112;                         // 128 f
    float* shs  = ws + 20058240;                         // 128 f
    unsigned short* wfr = (unsigned short*)(ws + 20058368);  // 221,184 ush

    unsigned short* wproj_f = wfr;
    unsigned short* woff_f  = wfr + 32768;
    unsigned short* wmask_f = wfr + 69632;
    unsigned short* wfc1_f  = wfr + 90112;
    unsigned short* wfc2_f  = wfr + 155648;

    k_wprep<<<216, 64, 0, stream>>>(wproj, woff, wmask, wfc1, wfc2, wfr);
    k_aprep<<<2048, 256, 0, stream>>>(inp, inpf);
    k_border<<<260, 256, 0, stream>>>(xpad);
    k_fgemm<128,  8, 2, 3, 128><<<dim3(256, 4), 256, 0, stream>>>(inpf, wproj_f, bproj, xpad, 0, nullptr);
    k_dwconv<<<512, 256, 0, stream>>>(inp, dww, dwb, ydw, psum, psq);
    k_bnstats<<<128, 256, 0, stream>>>(psum, psq, gamma, beta, scs, shs);
    k_bngelu<<<2048, 256, 0, stream>>>(ydw, scs, shs, x1f);
    k_fgemm<128,  9, 3, 0, 144><<<dim3(256, 3), 256, 0, stream>>>(x1f, woff_f, boff, offs, 144, nullptr);
    k_fgemm<128,  5, 3, 0,  72><<<dim3(256, 2), 256, 0, stream>>>(x1f, wmask_f, bmask, msk, 72, nullptr);
    k_dcn<<<4096, 256, 0, stream>>>(xpad, offs, msk, dcnf);
    k_fgemm<128, 16, 4, 1, 256><<<dim3(256, 4), 256, 0, stream>>>(dcnf, wfc1_f, bfc1, nullptr, 0, hdnf);
    k_fgemm<256,  8, 2, 2, 128><<<dim3(256, 4), 256, 0, stream>>>(hdnf, wfc2_f, bfc2, out, 0, nullptr);
}

// Round 7
// 135.406 us; speedup vs baseline: 1.2524x; 1.0654x over previous
//
#include <hip/hip_runtime.h>
#include <math.h>

#define NPOS  32768      // B*H*W
#define CDIM  128
#define HS    64
#define WSZ   64

typedef __bf16 bf8_t  __attribute__((ext_vector_type(8)));
typedef float  f32x4  __attribute__((ext_vector_type(4)));

__device__ __forceinline__ float gelu_exact(float x) {
    return 0.5f * x * (1.0f + erff(x * 0.70710678118654752f));
}

__device__ __forceinline__ void hilo(float v, unsigned& h, unsigned& l) {
    __bf16 hb = (__bf16)v;
    h = (unsigned)__builtin_bit_cast(unsigned short, hb);
    __bf16 lb = (__bf16)(v - (float)hb);
    l = (unsigned)__builtin_bit_cast(unsigned short, lb);
}

__device__ __forceinline__ void pack8(const float* v, uint4& hi, uint4& lo) {
    unsigned hh[8], ll[8];
    #pragma unroll
    for (int i = 0; i < 8; ++i) hilo(v[i], hh[i], ll[i]);
    hi = make_uint4(hh[0] | (hh[1] << 16), hh[2] | (hh[3] << 16),
                    hh[4] | (hh[5] << 16), hh[6] | (hh[7] << 16));
    lo = make_uint4(ll[0] | (ll[1] << 16), ll[2] | (ll[3] << 16),
                    ll[4] | (ll[5] << 16), ll[6] | (ll[7] << 16));
}

// unpack uint4 (8 bf16) and fma into acc[8] with weight
__device__ __forceinline__ void ufma(float* acc, uint4 c, float wgt) {
    const unsigned* cc = (const unsigned*)&c;
    #pragma unroll
    for (int j = 0; j < 4; ++j) {
        acc[2 * j]     += __builtin_bit_cast(float, cc[j] << 16) * wgt;
        acc[2 * j + 1] += __builtin_bit_cast(float, cc[j] & 0xFFFF0000u) * wgt;
    }
}

// ---------------------------------------------------------------------------
// A-frag layout (K=KC*32): ushort buffer; block(rt,kc) at (rt*KC+kc)*1024,
// hi elem: lane*8 + i  (lane = (row%16) + ((k%32)/8)*16, i = k%8), lo at +512.
// ---------------------------------------------------------------------------

// K_aprep: fp32 row-major [32768][128] -> frag hi/lo. grid 2048, block 256.
__global__ __launch_bounds__(256) void k_aprep(
    const float* __restrict__ src, unsigned short* __restrict__ dst)
{
    int idx = blockIdx.x * 256 + threadIdx.x;   // 32768*16
    int r = idx >> 4, k8 = (idx & 15) * 8;
    float t[8];
    *(float4*)(t)     = *(const float4*)(src + (size_t)r * 128 + k8);
    *(float4*)(t + 4) = *(const float4*)(src + (size_t)r * 128 + k8 + 4);
    uint4 hi, lo;
    pack8(t, hi, lo);
    int rt = r >> 4, kc = k8 >> 5, lp = (r & 15) + ((k8 & 31) >> 3) * 16;
    size_t base = ((size_t)rt * 4 + kc) * 1024 + lp * 8;
    *(uint4*)(dst + base)       = hi;
    *(uint4*)(dst + base + 512) = lo;
}

// K_border: zero the 1-px ring of bf16 xpad[b][66][66][128]. grid 130, block 256.
__global__ __launch_bounds__(256) void k_border(unsigned short* __restrict__ xpad)
{
    int idx = blockIdx.x * 256 + threadIdx.x;  // 2080 cells * 16 = 33280
    int c8 = (idx & 15) * 8;
    int cell = idx >> 4;                       // 0..2079
    int b = cell / 260, r = cell % 260;
    int h, w;
    if (r < 66)       { h = 0;  w = r; }
    else if (r < 132) { h = 65; w = r - 66; }
    else { int rr = r - 132; h = 1 + (rr >> 1); w = (rr & 1) * 65; }
    size_t o = (((size_t)b * 66 + h) * 66 + w) * 128 + c8;
    *(uint4*)(xpad + o) = make_uint4(0u, 0u, 0u, 0u);
}

// ---------------------------------------------------------------------------
// K1: depthwise 3x3 conv (NHWC) + per-block partial BN sums
// ---------------------------------------------------------------------------
__global__ __launch_bounds__(256) void k_dwconv(
    const float* __restrict__ inp, const float* __restrict__ dww,
    const float* __restrict__ dwb, float* __restrict__ ydw,
    float* __restrict__ psum, float* __restrict__ psq)
{
    int blk = blockIdx.x;            // b*64 + h
    int b = blk >> 6, h = blk & 63;
    int tid = threadIdx.x;
    int c4 = (tid & 31) * 4;
    int wg = tid >> 5;               // 0..7

    float wreg[4][9];
    #pragma unroll
    for (int cc = 0; cc < 4; ++cc)
        #pragma unroll
        for (int p = 0; p < 9; ++p)
            wreg[cc][p] = dww[(c4 + cc) * 9 + p];
    float bia[4];
    #pragma unroll
    for (int cc = 0; cc < 4; ++cc) bia[cc] = dwb[c4 + cc];

    float s4[4] = {0,0,0,0}, q4[4] = {0,0,0,0};
    const float* ibase = inp + (size_t)(b << 12) * CDIM;

    for (int i = 0; i < 8; ++i) {
        int w = wg + i * 8;
        float acc[4] = {bia[0], bia[1], bia[2], bia[3]};
        #pragma unroll
        for (int ky = 0; ky < 3; ++ky) {
            int yy = h + ky - 1;
            if (yy < 0 || yy >= HS) continue;
            #pragma unroll
            for (int kx = 0; kx < 3; ++kx) {
                int xx = w + kx - 1;
                if (xx < 0 || xx >= WSZ) continue;
                float4 v = *(const float4*)(ibase + (size_t)(yy * 64 + xx) * CDIM + c4);
                int p = ky * 3 + kx;
                acc[0] += v.x * wreg[0][p];
                acc[1] += v.y * wreg[1][p];
                acc[2] += v.z * wreg[2][p];
                acc[3] += v.w * wreg[3][p];
            }
        }
        float4 o = {acc[0], acc[1], acc[2], acc[3]};
        *(float4*)(ydw + ((size_t)(b << 12) + h * 64 + w) * CDIM + c4) = o;
        #pragma unroll
        for (int cc = 0; cc < 4; ++cc) { s4[cc] += acc[cc]; q4[cc] += acc[cc] * acc[cc]; }
    }

    __shared__ float ls[8][128], lq[8][128];
    #pragma unroll
    for (int cc = 0; cc < 4; ++cc) { ls[wg][c4 + cc] = s4[cc]; lq[wg][c4 + cc] = q4[cc]; }
    __syncthreads();
    if (tid < 128) {
        float s = 0.f, q = 0.f;
        #pragma unroll
        for (int r = 0; r < 8; ++r) { s += ls[r][tid]; q += lq[r][tid]; }
        psum[blk * 128 + tid] = s;
        psq [blk * 128 + tid] = q;
    }
}

// ---------------------------------------------------------------------------
// K2: finalize BN stats -> scale/shift per channel.
// ---------------------------------------------------------------------------
__global__ __launch_bounds__(256) void k_bnstats(
    const float* __restrict__ psum, const float* __restrict__ psq,
    const float* __restrict__ gamma, const float* __restrict__ beta,
    float* __restrict__ sc, float* __restrict__ sh)
{
    int c = blockIdx.x;
    int t = threadIdx.x;
    float s = psum[t * 128 + c] + psum[(t + 256) * 128 + c];
    float q = psq [t * 128 + c] + psq [(t + 256) * 128 + c];
    __shared__ float rs[256], rq[256];
    rs[t] = s; rq[t] = q; __syncthreads();
    for (int off = 128; off > 0; off >>= 1) {
        if (t < off) { rs[t] += rs[t + off]; rq[t] += rq[t + off]; }
        __syncthreads();
    }
    if (t == 0) {
        float mean = rs[0] * (1.0f / 32768.0f);
        float var  = rq[0] * (1.0f / 32768.0f) - mean * mean;
        float scale = gamma[c] * rsqrtf(var + 1e-5f);
        sc[c] = scale;
        sh[c] = beta[c] - mean * scale;
    }
}

// ---------------------------------------------------------------------------
// K3: BN + exact GELU, ydw (fp32) -> x1 frag hi/lo. grid 2048, block 256.
// ---------------------------------------------------------------------------
__global__ __launch_bounds__(256) void k_bngelu(
    const float* __restrict__ ydw, const float* __restrict__ sc,
    const float* __restrict__ sh, unsigned short* __restrict__ dst)
{
    int idx = blockIdx.x * 256 + threadIdx.x;   // 32768*16
    int r = idx >> 4, k8 = (idx & 15) * 8;
    float t[8];
    *(float4*)(t)     = *(const float4*)(ydw + (size_t)r * 128 + k8);
    *(float4*)(t + 4) = *(const float4*)(ydw + (size_t)r * 128 + k8 + 4);
    float s[8], h[8];
    *(float4*)(s)     = *(const float4*)(sc + k8);
    *(float4*)(s + 4) = *(const float4*)(sc + k8 + 4);
    *(float4*)(h)     = *(const float4*)(sh + k8);
    *(float4*)(h + 4) = *(const float4*)(sh + k8 + 4);
    #pragma unroll
    for (int i = 0; i < 8; ++i) t[i] = gelu_exact(t[i] * s[i] + h[i]);
    uint4 hi, lo;
    pack8(t, hi, lo);
    int rt = r >> 4, kc = k8 >> 5, lp = (r & 15) + ((k8 & 31) >> 3) * 16;
    size_t base = ((size_t)rt * 4 + kc) * 1024 + lp * 8;
    *(uint4*)(dst + base)       = hi;
    *(uint4*)(dst + base + 512) = lo;
}

// ---------------------------------------------------------------------------
// K_wprep: weights W[N][K] fp32 -> fragment-ordered hi/lo bf16.
// ---------------------------------------------------------------------------
__global__ __launch_bounds__(64) void k_wprep(
    const float* __restrict__ w0, const float* __restrict__ w1,
    const float* __restrict__ w2, const float* __restrict__ w3,
    const float* __restrict__ w4, unsigned short* __restrict__ wb)
{
    int bid = blockIdx.x, lane = threadIdx.x;
    const float* W; int N, K, NT; unsigned short* out; int local;
    if (bid < 32)       { W = w0; N = 128; K = 128; NT = 8;  out = wb;          local = bid; }
    else if (bid < 68)  { W = w1; N = 144; K = 128; NT = 9;  out = wb + 32768;  local = bid - 32; }
    else if (bid < 88)  { W = w2; N = 72;  K = 128; NT = 5;  out = wb + 69632;  local = bid - 68; }
    else if (bid < 152) { W = w3; N = 256; K = 128; NT = 16; out = wb + 90112;  local = bid - 88; }
    else                { W = w4; N = 128; K = 256; NT = 8;  out = wb + 155648; local = bid - 152; }
    int KC = K / 32;
    int unit = KC * NT * 512;
    int kc = local / NT, t = local % NT;
    int n  = t * 16 + (lane & 15);
    int kb = kc * 32 + (lane >> 4) * 8;
    size_t base = ((size_t)local * 64 + lane) * 8;
    #pragma unroll
    for (int i = 0; i < 8; ++i) {
        float v = (n < N) ? W[(size_t)n * K + kb + i] : 0.f;
        __bf16 h = (__bf16)v;
        float  r = v - (float)h;
        __bf16 l = (__bf16)r;
        out[base + i]        = __builtin_bit_cast(unsigned short, h);
        out[unit + base + i] = __builtin_bit_cast(unsigned short, l);
    }
}

// ---------------------------------------------------------------------------
// Frag-stream MFMA GEMM, TLP+reuse version.
// grid: (rowtile_groups=256, n_chunks). block = 4 waves.
// wave = RT=2 rowtiles x NT_W n-tiles. hi/lo split -> 3 MFMAs, ~fp32 accuracy.
// MODE 0: fp32 row-major + bias. MODE 1: bias+GELU -> frag out.
// MODE 2: NCHW transposed store. MODE 3: bf16 padded [b][66][66][128] store.
// ---------------------------------------------------------------------------
template<int KDIM, int NT_TOT, int NT_W, int MODE, int NV>
__global__ __launch_bounds__(256) void k_fgemm(
    const unsigned short* __restrict__ AF, const unsigned short* __restrict__ WF,
    const float* __restrict__ bias, float* __restrict__ C, int ldc,
    unsigned short* __restrict__ OF)
{
    constexpr int KC = KDIM / 32;
    int tid = threadIdx.x;
    int lane = tid & 63, w = tid >> 6;
    int rt0 = blockIdx.x * 8 + w * 2;      // 2 rowtiles per wave
    int t0 = blockIdx.y * NT_W;            // n-tile chunk base

    f32x4 acc[2][NT_W];
    #pragma unroll
    for (int rt = 0; rt < 2; ++rt)
        #pragma unroll
        for (int t = 0; t < NT_W; ++t) acc[rt][t] = (f32x4){0.f, 0.f, 0.f, 0.f};

    const bf8_t* Ab0 = (const bf8_t*)AF + (size_t)rt0 * KC * 128 + lane;
    const bf8_t* Ab1 = Ab0 + KC * 128;
    const bf8_t* WHp = (const bf8_t*)WF + lane;
    const bf8_t* WLp = WHp + KC * NT_TOT * 64;

    #pragma unroll
    for (int kc = 0; kc < KC; ++kc) {
        bf8_t a0h = Ab0[kc * 128];
        bf8_t a0l = Ab0[kc * 128 + 64];
        bf8_t a1h = Ab1[kc * 128];
        bf8_t a1l = Ab1[kc * 128 + 64];
        #pragma unroll
        for (int t = 0; t < NT_W; ++t) {
            int tg = t0 + t;
            if (tg < NT_TOT) {
                bf8_t wh = WHp[(kc * NT_TOT + tg) * 64];
                bf8_t wl = WLp[(kc * NT_TOT + tg) * 64];
                if (MODE == 2) {
                    acc[0][t] = __builtin_amdgcn_mfma_f32_16x16x32_bf16(a0h, wh, acc[0][t], 0, 0, 0);
                    acc[0][t] = __builtin_amdgcn_mfma_f32_16x16x32_bf16(a0l, wh, acc[0][t], 0, 0, 0);
                    acc[0][t] = __builtin_amdgcn_mfma_f32_16x16x32_bf16(a0h, wl, acc[0][t], 0, 0, 0);
                    acc[1][t] = __builtin_amdgcn_mfma_f32_16x16x32_bf16(a1h, wh, acc[1][t], 0, 0, 0);
                    acc[1][t] = __builtin_amdgcn_mfma_f32_16x16x32_bf16(a1l, wh, acc[1][t], 0, 0, 0);
                    acc[1][t] = __builtin_amdgcn_mfma_f32_16x16x32_bf16(a1h, wl, acc[1][t], 0, 0, 0);
                } else {
                    acc[0][t] = __builtin_amdgcn_mfma_f32_16x16x32_bf16(wh, a0h, acc[0][t], 0, 0, 0);
                    acc[0][t] = __builtin_amdgcn_mfma_f32_16x16x32_bf16(wh, a0l, acc[0][t], 0, 0, 0);
                    acc[0][t] = __builtin_amdgcn_mfma_f32_16x16x32_bf16(wl, a0h, acc[0][t], 0, 0, 0);
                    acc[1][t] = __builtin_amdgcn_mfma_f32_16x16x32_bf16(wh, a1h, acc[1][t], 0, 0, 0);
                    acc[1][t] = __builtin_amdgcn_mfma_f32_16x16x32_bf16(wh, a1l, acc[1][t], 0, 0, 0);
                    acc[1][t] = __builtin_amdgcn_mfma_f32_16x16x32_bf16(wl, a1h, acc[1][t], 0, 0, 0);
                }
            }
        }
    }

    #pragma unroll
    for (int rt = 0; rt < 2; ++rt) {
        if (MODE == 0) {
            int m = (rt0 + rt) * 16 + (lane & 15);
            #pragma unroll
            for (int t = 0; t < NT_W; ++t) {
                int tg = t0 + t;
                int nb = tg * 16 + ((lane >> 4) << 2);
                if (tg < NT_TOT && nb + 4 <= NV) {
                    float4 bb = *(const float4*)(bias + nb);
                    f32x4 a = acc[rt][t];
                    float4 v = {a[0] + bb.x, a[1] + bb.y, a[2] + bb.z, a[3] + bb.w};
                    *(float4*)(C + (size_t)m * ldc + nb) = v;
                }
            }
        } else if (MODE == 1) {
            int m = (rt0 + rt) * 16 + (lane & 15);
            #pragma unroll
            for (int t = 0; t < NT_W; ++t) {
                int tg = t0 + t;
                if (tg < NT_TOT) {
                    int nb = tg * 16 + ((lane >> 4) << 2);
                    float4 bb = *(const float4*)(bias + nb);
                    f32x4 a = acc[rt][t];
                    float v[4];
                    v[0] = gelu_exact(a[0] + bb.x); v[1] = gelu_exact(a[1] + bb.y);
                    v[2] = gelu_exact(a[2] + bb.z); v[3] = gelu_exact(a[3] + bb.w);
                    unsigned hh[4], ll[4];
                    #pragma unroll
                    for (int i = 0; i < 4; ++i) hilo(v[i], hh[i], ll[i]);
                    uint2 hi = make_uint2(hh[0] | (hh[1] << 16), hh[2] | (hh[3] << 16));
                    uint2 lo = make_uint2(ll[0] | (ll[1] << 16), ll[2] | (ll[3] << 16));
                    int kco = nb >> 5, lp = (m & 15) + ((nb & 31) >> 3) * 16;
                    size_t fb = ((size_t)(rt0 + rt) * (NV / 32) + kco) * 1024 + lp * 8 + (nb & 7);
                    *(uint2*)(OF + fb)       = hi;
                    *(uint2*)(OF + fb + 512) = lo;
                }
            }
        } else if (MODE == 3) {
            // bf16 store into zero-padded [b][66][66][128]
            unsigned short* Cp = (unsigned short*)C;
            int m = (rt0 + rt) * 16 + (lane & 15);
            int bb_ = m >> 12, hwm = m & 4095;
            size_t rowb = (((size_t)bb_ * 66 + (hwm >> 6) + 1) * 66 + (hwm & 63) + 1) * 128;
            #pragma unroll
            for (int t = 0; t < NT_W; ++t) {
                int tg = t0 + t;
                int nb = tg * 16 + ((lane >> 4) << 2);
                if (tg < NT_TOT) {
                    float4 bb = *(const float4*)(bias + nb);
                    f32x4 a = acc[rt][t];
                    ushort4 v;
                    v.x = __builtin_bit_cast(unsigned short, (__bf16)(a[0] + bb.x));
                    v.y = __builtin_bit_cast(unsigned short, (__bf16)(a[1] + bb.y));
                    v.z = __builtin_bit_cast(unsigned short, (__bf16)(a[2] + bb.z));
                    v.w = __builtin_bit_cast(unsigned short, (__bf16)(a[3] + bb.w));
                    *(ushort4*)(Cp + rowb + nb) = v;
                }
            }
        } else {
            int m4 = (rt0 + rt) * 16 + ((lane >> 4) << 2);
            int b = m4 >> 12, hw = m4 & 4095;
            #pragma unroll
            for (int t = 0; t < NT_W; ++t) {
                int tg = t0 + t;
                if (tg < NT_TOT) {
                    int n = tg * 16 + (lane & 15);
                    float bb = bias[n];
                    f32x4 a = acc[rt][t];
                    float4 v = {a[0] + bb, a[1] + bb, a[2] + bb, a[3] + bb};
                    *(float4*)(C + (((size_t)(b * 128 + n)) << 12) + hw) = v;
                }
            }
        }
    }
}

// ---------------------------------------------------------------------------
// K6: DCNv3 core v4. thread = (pos, g, half), 8 channels. grid 2048.
// bf16 xpad gathers (uint4 = 8ch), unconditional clamped addressing.
// Softmax redundant x2. Output packed directly as fc1 A-frags (hi/lo).
// ---------------------------------------------------------------------------
__global__ __launch_bounds__(256) void k_dcn(
    const unsigned short* __restrict__ xpad, const float* __restrict__ offs,
    const float* __restrict__ msk, unsigned short* __restrict__ dcnf)
{
    int u = blockIdx.x * 256 + threadIdx.x;  // 32768*8*2
    int q = u & 1;
    int g = (u >> 1) & 7;
    int pos = u >> 4;
    int b = pos >> 12, hw = pos & 4095, h = hw >> 6, w = hw & 63;

    const float* ml = msk + (size_t)pos * 72 + g * 9;
    float e[9];
    float mx = -1e30f;
    #pragma unroll
    for (int p = 0; p < 9; ++p) { e[p] = ml[p]; mx = fmaxf(mx, e[p]); }
    float ssum = 0.f;
    #pragma unroll
    for (int p = 0; p < 9; ++p) { e[p] = __expf(e[p] - mx); ssum += e[p]; }
    float inv = 1.0f / ssum;

    const float2* ob2 = (const float2*)(offs + (size_t)pos * 144 + g * 18);
    int ch = g * 16 + q * 8;
    const unsigned short* xb = xpad + (size_t)b * 557568 + ch;  // 66*66*128/batch

    float acc[8] = {0.f, 0.f, 0.f, 0.f, 0.f, 0.f, 0.f, 0.f};

    #pragma unroll
    for (int p = 0; p < 9; ++p) {
        float2 d = ob2[p];
        float px = (float)(w + (p % 3)) + d.x;   // padded-grid coords
        float py = (float)(h + (p / 3)) + d.y;
        float x0f = floorf(px), y0f = floorf(py);
        float wx = px - x0f, wy = py - y0f;
        int ix = (int)x0f, iy = (int)y0f;
        int ix0 = max(min(ix, 65), 0),     ix1 = max(min(ix + 1, 65), 0);
        int iy0 = max(min(iy, 65), 0),     iy1 = max(min(iy + 1, 65), 0);
        int r0 = iy0 * 66, r1 = iy1 * 66;

        float mp  = e[p] * inv;
        float w11 = wy * wx * mp;
        float w10 = wy * mp - w11;
        float w01 = wx * mp - w11;
        float w00 = mp - w01 - w10 - w11;

        uint4 s00 = *(const uint4*)(xb + (size_t)(r0 + ix0) * 128);
        uint4 s01 = *(const uint4*)(xb + (size_t)(r0 + ix1) * 128);
        uint4 s10 = *(const uint4*)(xb + (size_t)(r1 + ix0) * 128);
        uint4 s11 = *(const uint4*)(xb + (size_t)(r1 + ix1) * 128);

        ufma(acc, s00, w00);
        ufma(acc, s01, w01);
        ufma(acc, s10, w10);
        ufma(acc, s11, w11);
    }

    uint4 hi, lo;
    pack8(acc, hi, lo);
    int rt = pos >> 4, kcf = ch >> 5, lp = (pos & 15) + ((ch & 31) >> 3) * 16;
    size_t fb = ((size_t)rt * 4 + kcf) * 1024 + (size_t)lp * 8;
    *(uint4*)(dcnf + fb)       = hi;
    *(uint4*)(dcnf + fb + 512) = lo;
}

// ---------------------------------------------------------------------------
extern "C" void kernel_launch(void* const* d_in, const int* in_sizes, int n_in,
                              void* d_out, int out_size, void* d_ws, size_t ws_size,
                              hipStream_t stream)
{
    const float* inp   = (const float*)d_in[0];
    const float* wproj = (const float*)d_in[1];
    const float* bproj = (const float*)d_in[2];
    const float* dww   = (const float*)d_in[3];
    const float* dwb   = (const float*)d_in[4];
    const float* gamma = (const float*)d_in[5];
    const float* beta  = (const float*)d_in[6];
    const float* woff  = (const float*)d_in[7];
    const float* boff  = (const float*)d_in[8];
    const float* wmask = (const float*)d_in[9];
    const float* bmask = (const float*)d_in[10];
    const float* wfc1  = (const float*)d_in[11];
    const float* bfc1  = (const float*)d_in[12];
    const float* wfc2  = (const float*)d_in[13];
    const float* bfc2  = (const float*)d_in[14];
    float* out = (float*)d_out;
    float* ws  = (float*)d_ws;

    // Region P: xpad (bf16) + offs; later hdnf (fc1 out frags)
    unsigned short* xpad = (unsigned short*)ws;          // 4,460,544 ush = 2,230,272 f
    float* offs = ws + 2230272;                          // 4,718,592 f -> ends 6,948,864
    unsigned short* hdnf = (unsigned short*)ws;          // 16,777,216 ush = 8,388,608 f [fc1..fc2]
    // Region A [9179136, 17567744): time-shared
    float* ydw            = ws + 9179136;                // 4,194,304 f [dwconv..bngelu]
    unsigned short* inpf  = (unsigned short*)(ws + 9179136);   // [aprep..proj]
    unsigned short* dcnf  = (unsigned short*)(ws + 9179136);   // [dcn..fc1]
    unsigned short* x1f   = (unsigned short*)(ws + 13373440);  // [bngelu..mask]
    // Rest
    float* msk  = ws + 17567744;                         // 2,359,296 f
    float* psum = ws + 19927040;                         // 65,536 f
    float* psq  = ws + 19992576;                         // 65,536 f
    float* scs  = ws + 20058112;                         // 128 f
    float* shs  = ws + 20058240;                         // 128 f
    unsigned short* wfr = (unsigned short*)(ws + 20058368);  // 221,184 ush

    unsigned short* wproj_f = wfr;
    unsigned short* woff_f  = wfr + 32768;
    unsigned short* wmask_f = wfr + 69632;
    unsigned short* wfc1_f  = wfr + 90112;
    unsigned short* wfc2_f  = wfr + 155648;

    k_wprep<<<216, 64, 0, stream>>>(wproj, woff, wmask, wfc1, wfc2, wfr);
    k_aprep<<<2048, 256, 0, stream>>>(inp, inpf);
    k_border<<<130, 256, 0, stream>>>(xpad);
    k_fgemm<128,  8, 2, 3, 128><<<dim3(256, 4), 256, 0, stream>>>(inpf, wproj_f, bproj, (float*)xpad, 0, nullptr);
    k_dwconv<<<512, 256, 0, stream>>>(inp, dww, dwb, ydw, psum, psq);
    k_bnstats<<<128, 256, 0, stream>>>(psum, psq, gamma, beta, scs, shs);
    k_bngelu<<<2048, 256, 0, stream>>>(ydw, scs, shs, x1f);
    k_fgemm<128,  9, 3, 0, 144><<<dim3(256, 3), 256, 0, stream>>>(x1f, woff_f, boff, offs, 144, nullptr);
    k_fgemm<128,  5, 3, 0,  72><<<dim3(256, 2), 256, 0, stream>>>(x1f, wmask_f, bmask, msk, 72, nullptr);
    k_dcn<<<2048, 256, 0, stream>>>(xpad, offs, msk, dcnf);
    k_fgemm<128, 16, 4, 1, 256><<<dim3(256, 4), 256, 0, stream>>>(dcnf, wfc1_f, bfc1, nullptr, 0, hdnf);
    k_fgemm<256,  8, 2, 2, 128><<<dim3(256, 4), 256, 0, stream>>>(hdnf, wfc2_f, bfc2, out, 0, nullptr);
}

// Round 8
// 129.786 us; speedup vs baseline: 1.3066x; 1.0433x over previous
//
#include <hip/hip_runtime.h>
#include <math.h>

#define NPOS  32768      // B*H*W
#define CDIM  128
#define HS    64
#define WSZ   64

typedef __bf16 bf8_t  __attribute__((ext_vector_type(8)));
typedef float  f32x4  __attribute__((ext_vector_type(4)));

__device__ __forceinline__ float gelu_exact(float x) {
    return 0.5f * x * (1.0f + erff(x * 0.70710678118654752f));
}

__device__ __forceinline__ void hilo(float v, unsigned& h, unsigned& l) {
    __bf16 hb = (__bf16)v;
    h = (unsigned)__builtin_bit_cast(unsigned short, hb);
    __bf16 lb = (__bf16)(v - (float)hb);
    l = (unsigned)__builtin_bit_cast(unsigned short, lb);
}

__device__ __forceinline__ void pack8(const float* v, uint4& hi, uint4& lo) {
    unsigned hh[8], ll[8];
    #pragma unroll
    for (int i = 0; i < 8; ++i) hilo(v[i], hh[i], ll[i]);
    hi = make_uint4(hh[0] | (hh[1] << 16), hh[2] | (hh[3] << 16),
                    hh[4] | (hh[5] << 16), hh[6] | (hh[7] << 16));
    lo = make_uint4(ll[0] | (ll[1] << 16), ll[2] | (ll[3] << 16),
                    ll[4] | (ll[5] << 16), ll[6] | (ll[7] << 16));
}

__device__ __forceinline__ uint4 pack8hi(const float* v) {
    unsigned hh[8];
    #pragma unroll
    for (int i = 0; i < 8; ++i)
        hh[i] = (unsigned)__builtin_bit_cast(unsigned short, (__bf16)v[i]);
    return make_uint4(hh[0] | (hh[1] << 16), hh[2] | (hh[3] << 16),
                      hh[4] | (hh[5] << 16), hh[6] | (hh[7] << 16));
}

// unpack uint4 (8 bf16) and fma into acc[8] with weight
__device__ __forceinline__ void ufma(float* acc, uint4 c, float wgt) {
    const unsigned* cc = (const unsigned*)&c;
    #pragma unroll
    for (int j = 0; j < 4; ++j) {
        acc[2 * j]     += __builtin_bit_cast(float, cc[j] << 16) * wgt;
        acc[2 * j + 1] += __builtin_bit_cast(float, cc[j] & 0xFFFF0000u) * wgt;
    }
}

// ---------------------------------------------------------------------------
// A-frag layouts (K=KC*32):
//  hi/lo buffers: block(rt,kc) = 1024 ush (hi 512 | lo 512)
//  hi-only buffers: block(rt,kc) = 512 ush
//  elem: lane*8 + i, lane = (row%16) + ((k%32)/8)*16, i = k%8
// ---------------------------------------------------------------------------

// K_aprep: fp32 [32768][128] -> hi-only frags. grid 2048, block 256.
__global__ __launch_bounds__(256) void k_aprep(
    const float* __restrict__ src, unsigned short* __restrict__ dst)
{
    int idx = blockIdx.x * 256 + threadIdx.x;   // 32768*16
    int r = idx >> 4, k8 = (idx & 15) * 8;
    float t[8];
    *(float4*)(t)     = *(const float4*)(src + (size_t)r * 128 + k8);
    *(float4*)(t + 4) = *(const float4*)(src + (size_t)r * 128 + k8 + 4);
    uint4 hi = pack8hi(t);
    int rt = r >> 4, kc = k8 >> 5, lp = (r & 15) + ((k8 & 31) >> 3) * 16;
    size_t base = ((size_t)rt * 4 + kc) * 512 + lp * 8;
    *(uint4*)(dst + base) = hi;
}

// K_border: zero the 1-px ring of bf16 xpad[b][66][66][128]. grid 130, block 256.
__global__ __launch_bounds__(256) void k_border(unsigned short* __restrict__ xpad)
{
    int idx = blockIdx.x * 256 + threadIdx.x;  // 2080 cells * 16 = 33280
    int c8 = (idx & 15) * 8;
    int cell = idx >> 4;                       // 0..2079
    int b = cell / 260, r = cell % 260;
    int h, w;
    if (r < 66)       { h = 0;  w = r; }
    else if (r < 132) { h = 65; w = r - 66; }
    else { int rr = r - 132; h = 1 + (rr >> 1); w = (rr & 1) * 65; }
    size_t o = (((size_t)b * 66 + h) * 66 + w) * 128 + c8;
    *(uint4*)(xpad + o) = make_uint4(0u, 0u, 0u, 0u);
}

// ---------------------------------------------------------------------------
// K1: depthwise 3x3 conv (NHWC) + per-block partial BN sums
// ---------------------------------------------------------------------------
__global__ __launch_bounds__(256) void k_dwconv(
    const float* __restrict__ inp, const float* __restrict__ dww,
    const float* __restrict__ dwb, float* __restrict__ ydw,
    float* __restrict__ psum, float* __restrict__ psq)
{
    int blk = blockIdx.x;            // b*64 + h
    int b = blk >> 6, h = blk & 63;
    int tid = threadIdx.x;
    int c4 = (tid & 31) * 4;
    int wg = tid >> 5;               // 0..7

    float wreg[4][9];
    #pragma unroll
    for (int cc = 0; cc < 4; ++cc)
        #pragma unroll
        for (int p = 0; p < 9; ++p)
            wreg[cc][p] = dww[(c4 + cc) * 9 + p];
    float bia[4];
    #pragma unroll
    for (int cc = 0; cc < 4; ++cc) bia[cc] = dwb[c4 + cc];

    float s4[4] = {0,0,0,0}, q4[4] = {0,0,0,0};
    const float* ibase = inp + (size_t)(b << 12) * CDIM;

    for (int i = 0; i < 8; ++i) {
        int w = wg + i * 8;
        float acc[4] = {bia[0], bia[1], bia[2], bia[3]};
        #pragma unroll
        for (int ky = 0; ky < 3; ++ky) {
            int yy = h + ky - 1;
            if (yy < 0 || yy >= HS) continue;
            #pragma unroll
            for (int kx = 0; kx < 3; ++kx) {
                int xx = w + kx - 1;
                if (xx < 0 || xx >= WSZ) continue;
                float4 v = *(const float4*)(ibase + (size_t)(yy * 64 + xx) * CDIM + c4);
                int p = ky * 3 + kx;
                acc[0] += v.x * wreg[0][p];
                acc[1] += v.y * wreg[1][p];
                acc[2] += v.z * wreg[2][p];
                acc[3] += v.w * wreg[3][p];
            }
        }
        float4 o = {acc[0], acc[1], acc[2], acc[3]};
        *(float4*)(ydw + ((size_t)(b << 12) + h * 64 + w) * CDIM + c4) = o;
        #pragma unroll
        for (int cc = 0; cc < 4; ++cc) { s4[cc] += acc[cc]; q4[cc] += acc[cc] * acc[cc]; }
    }

    __shared__ float ls[8][128], lq[8][128];
    #pragma unroll
    for (int cc = 0; cc < 4; ++cc) { ls[wg][c4 + cc] = s4[cc]; lq[wg][c4 + cc] = q4[cc]; }
    __syncthreads();
    if (tid < 128) {
        float s = 0.f, q = 0.f;
        #pragma unroll
        for (int r = 0; r < 8; ++r) { s += ls[r][tid]; q += lq[r][tid]; }
        psum[blk * 128 + tid] = s;
        psq [blk * 128 + tid] = q;
    }
}

// ---------------------------------------------------------------------------
// K2: finalize BN stats -> scale/shift per channel.
// ---------------------------------------------------------------------------
__global__ __launch_bounds__(256) void k_bnstats(
    const float* __restrict__ psum, const float* __restrict__ psq,
    const float* __restrict__ gamma, const float* __restrict__ beta,
    float* __restrict__ sc, float* __restrict__ sh)
{
    int c = blockIdx.x;
    int t = threadIdx.x;
    float s = psum[t * 128 + c] + psum[(t + 256) * 128 + c];
    float q = psq [t * 128 + c] + psq [(t + 256) * 128 + c];
    __shared__ float rs[256], rq[256];
    rs[t] = s; rq[t] = q; __syncthreads();
    for (int off = 128; off > 0; off >>= 1) {
        if (t < off) { rs[t] += rs[t + off]; rq[t] += rq[t + off]; }
        __syncthreads();
    }
    if (t == 0) {
        float mean = rs[0] * (1.0f / 32768.0f);
        float var  = rq[0] * (1.0f / 32768.0f) - mean * mean;
        float scale = gamma[c] * rsqrtf(var + 1e-5f);
        sc[c] = scale;
        sh[c] = beta[c] - mean * scale;
    }
}

// ---------------------------------------------------------------------------
// K3: BN + exact GELU, ydw (fp32) -> x1 hi-only frags. grid 2048, block 256.
// ---------------------------------------------------------------------------
__global__ __launch_bounds__(256) void k_bngelu(
    const float* __restrict__ ydw, const float* __restrict__ sc,
    const float* __restrict__ sh, unsigned short* __restrict__ dst)
{
    int idx = blockIdx.x * 256 + threadIdx.x;   // 32768*16
    int r = idx >> 4, k8 = (idx & 15) * 8;
    float t[8];
    *(float4*)(t)     = *(const float4*)(ydw + (size_t)r * 128 + k8);
    *(float4*)(t + 4) = *(const float4*)(ydw + (size_t)r * 128 + k8 + 4);
    float s[8], h[8];
    *(float4*)(s)     = *(const float4*)(sc + k8);
    *(float4*)(s + 4) = *(const float4*)(sc + k8 + 4);
    *(float4*)(h)     = *(const float4*)(sh + k8);
    *(float4*)(h + 4) = *(const float4*)(sh + k8 + 4);
    #pragma unroll
    for (int i = 0; i < 8; ++i) t[i] = gelu_exact(t[i] * s[i] + h[i]);
    uint4 hi = pack8hi(t);
    int rt = r >> 4, kc = k8 >> 5, lp = (r & 15) + ((k8 & 31) >> 3) * 16;
    size_t base = ((size_t)rt * 4 + kc) * 512 + lp * 8;
    *(uint4*)(dst + base) = hi;
}

// ---------------------------------------------------------------------------
// K_wprep: weights -> fragment-ordered bf16.
//  seg0 proj:  NT=8,  K=128, hi-only          at wb + 0      (16384)
//  seg1 womb:  NT=14, K=128, hi-only combined at wb + 16384  (28672)
//              tiles 0..8 = w_off (144 rows), 9..13 = w_mask (72 rows, pad)
//  seg2 fc1:   NT=16, K=128, hi/lo            at wb + 45056  (65536)
//  seg3 fc2:   NT=8,  K=256, hi/lo            at wb + 110592 (65536)
// ---------------------------------------------------------------------------
__global__ __launch_bounds__(64) void k_wprep(
    const float* __restrict__ w0, const float* __restrict__ w1,
    const float* __restrict__ w2, const float* __restrict__ w3,
    const float* __restrict__ w4, unsigned short* __restrict__ wb)
{
    int bid = blockIdx.x, lane = threadIdx.x;
    int NT, K, local; unsigned short* out; bool hl; bool comb = false;
    const float* W = nullptr; int N = 0;
    if (bid < 32)       { NT = 8;  K = 128; out = wb;          local = bid;       hl = false; W = w0; N = 128; }
    else if (bid < 88)  { NT = 14; K = 128; out = wb + 16384;  local = bid - 32;  hl = false; comb = true; }
    else if (bid < 152) { NT = 16; K = 128; out = wb + 45056;  local = bid - 88;  hl = true;  W = w3; N = 256; }
    else                { NT = 8;  K = 256; out = wb + 110592; local = bid - 152; hl = true;  W = w4; N = 128; }
    int KC = K / 32;
    int unit = KC * NT * 512;
    int kc = local / NT, t = local % NT;
    int nt = t * 16 + (lane & 15);
    const float* Wp = W; int n = nt, Nv = N;
    if (comb) {
        if (t < 9) { Wp = w1; n = nt;       Nv = 144; }
        else       { Wp = w2; n = nt - 144; Nv = 72;  }
    }
    int kb = kc * 32 + (lane >> 4) * 8;
    size_t base = ((size_t)local * 64 + lane) * 8;
    #pragma unroll
    for (int i = 0; i < 8; ++i) {
        float v = (n < Nv) ? Wp[(size_t)n * K + kb + i] : 0.f;
        __bf16 h = (__bf16)v;
        out[base + i] = __builtin_bit_cast(unsigned short, h);
        if (hl) {
            __bf16 l = (__bf16)(v - (float)h);
            out[unit + base + i] = __builtin_bit_cast(unsigned short, l);
        }
    }
}

// ---------------------------------------------------------------------------
// Frag-stream MFMA GEMM.
// PREC 3: hi/lo A and W (3 MFMAs, ~fp32). PREC 1: hi-only (1 MFMA, bf16).
// MODE 0: fp32 row-major + bias. MODE 1: bias+GELU -> hi/lo frag out.
// MODE 2: NCHW transposed store. MODE 3: bf16 padded [b][66][66][128] store.
// MODE 4: split store: tiles 0..8 -> C (offs, ld 144), 9..13 -> C2 (msk, ld 72).
// ---------------------------------------------------------------------------
template<int KDIM, int NT_TOT, int NT_W, int MODE, int NV, int PREC>
__global__ __launch_bounds__(256) void k_fgemm(
    const unsigned short* __restrict__ AF, const unsigned short* __restrict__ WF,
    const float* __restrict__ bias, float* __restrict__ C, int ldc,
    unsigned short* __restrict__ OF, const float* __restrict__ bias2,
    float* __restrict__ C2)
{
    constexpr int KC = KDIM / 32;
    constexpr int ABLK = (PREC == 3) ? 128 : 64;   // bf8 units per (rt,kc) block
    int tid = threadIdx.x;
    int lane = tid & 63, w = tid >> 6;
    int rt0 = blockIdx.x * 8 + w * 2;      // 2 rowtiles per wave
    int t0 = blockIdx.y * NT_W;            // n-tile chunk base

    f32x4 acc[2][NT_W];
    #pragma unroll
    for (int rt = 0; rt < 2; ++rt)
        #pragma unroll
        for (int t = 0; t < NT_W; ++t) acc[rt][t] = (f32x4){0.f, 0.f, 0.f, 0.f};

    const bf8_t* Ab0 = (const bf8_t*)AF + (size_t)rt0 * KC * ABLK + lane;
    const bf8_t* Ab1 = Ab0 + KC * ABLK;
    const bf8_t* WHp = (const bf8_t*)WF + lane;
    const bf8_t* WLp = WHp + KC * NT_TOT * 64;

    #pragma unroll
    for (int kc = 0; kc < KC; ++kc) {
        bf8_t a0h = Ab0[kc * ABLK];
        bf8_t a1h = Ab1[kc * ABLK];
        bf8_t a0l, a1l;
        if (PREC == 3) { a0l = Ab0[kc * ABLK + 64]; a1l = Ab1[kc * ABLK + 64]; }
        #pragma unroll
        for (int t = 0; t < NT_W; ++t) {
            int tg = t0 + t;
            if (tg < NT_TOT) {
                bf8_t wh = WHp[(kc * NT_TOT + tg) * 64];
                if (MODE == 2) {
                    acc[0][t] = __builtin_amdgcn_mfma_f32_16x16x32_bf16(a0h, wh, acc[0][t], 0, 0, 0);
                    acc[1][t] = __builtin_amdgcn_mfma_f32_16x16x32_bf16(a1h, wh, acc[1][t], 0, 0, 0);
                    if (PREC == 3) {
                        bf8_t wl = WLp[(kc * NT_TOT + tg) * 64];
                        acc[0][t] = __builtin_amdgcn_mfma_f32_16x16x32_bf16(a0l, wh, acc[0][t], 0, 0, 0);
                        acc[0][t] = __builtin_amdgcn_mfma_f32_16x16x32_bf16(a0h, wl, acc[0][t], 0, 0, 0);
                        acc[1][t] = __builtin_amdgcn_mfma_f32_16x16x32_bf16(a1l, wh, acc[1][t], 0, 0, 0);
                        acc[1][t] = __builtin_amdgcn_mfma_f32_16x16x32_bf16(a1h, wl, acc[1][t], 0, 0, 0);
                    }
                } else {
                    acc[0][t] = __builtin_amdgcn_mfma_f32_16x16x32_bf16(wh, a0h, acc[0][t], 0, 0, 0);
                    acc[1][t] = __builtin_amdgcn_mfma_f32_16x16x32_bf16(wh, a1h, acc[1][t], 0, 0, 0);
                    if (PREC == 3) {
                        bf8_t wl = WLp[(kc * NT_TOT + tg) * 64];
                        acc[0][t] = __builtin_amdgcn_mfma_f32_16x16x32_bf16(wh, a0l, acc[0][t], 0, 0, 0);
                        acc[0][t] = __builtin_amdgcn_mfma_f32_16x16x32_bf16(wl, a0h, acc[0][t], 0, 0, 0);
                        acc[1][t] = __builtin_amdgcn_mfma_f32_16x16x32_bf16(wh, a1l, acc[1][t], 0, 0, 0);
                        acc[1][t] = __builtin_amdgcn_mfma_f32_16x16x32_bf16(wl, a1h, acc[1][t], 0, 0, 0);
                    }
                }
            }
        }
    }

    #pragma unroll
    for (int rt = 0; rt < 2; ++rt) {
        if (MODE == 0) {
            int m = (rt0 + rt) * 16 + (lane & 15);
            #pragma unroll
            for (int t = 0; t < NT_W; ++t) {
                int tg = t0 + t;
                int nb = tg * 16 + ((lane >> 4) << 2);
                if (tg < NT_TOT && nb + 4 <= NV) {
                    float4 bb = *(const float4*)(bias + nb);
                    f32x4 a = acc[rt][t];
                    float4 v = {a[0] + bb.x, a[1] + bb.y, a[2] + bb.z, a[3] + bb.w};
                    *(float4*)(C + (size_t)m * ldc + nb) = v;
                }
            }
        } else if (MODE == 1) {
            int m = (rt0 + rt) * 16 + (lane & 15);
            #pragma unroll
            for (int t = 0; t < NT_W; ++t) {
                int tg = t0 + t;
                if (tg < NT_TOT) {
                    int nb = tg * 16 + ((lane >> 4) << 2);
                    float4 bb = *(const float4*)(bias + nb);
                    f32x4 a = acc[rt][t];
                    float v[4];
                    v[0] = gelu_exact(a[0] + bb.x); v[1] = gelu_exact(a[1] + bb.y);
                    v[2] = gelu_exact(a[2] + bb.z); v[3] = gelu_exact(a[3] + bb.w);
                    unsigned hh[4], ll[4];
                    #pragma unroll
                    for (int i = 0; i < 4; ++i) hilo(v[i], hh[i], ll[i]);
                    uint2 hi = make_uint2(hh[0] | (hh[1] << 16), hh[2] | (hh[3] << 16));
                    uint2 lo = make_uint2(ll[0] | (ll[1] << 16), ll[2] | (ll[3] << 16));
                    int kco = nb >> 5, lp = (m & 15) + ((nb & 31) >> 3) * 16;
                    size_t fb = ((size_t)(rt0 + rt) * (NV / 32) + kco) * 1024 + lp * 8 + (nb & 7);
                    *(uint2*)(OF + fb)       = hi;
                    *(uint2*)(OF + fb + 512) = lo;
                }
            }
        } else if (MODE == 3) {
            // bf16 store into zero-padded [b][66][66][128]
            unsigned short* Cp = (unsigned short*)C;
            int m = (rt0 + rt) * 16 + (lane & 15);
            int bb_ = m >> 12, hwm = m & 4095;
            size_t rowb = (((size_t)bb_ * 66 + (hwm >> 6) + 1) * 66 + (hwm & 63) + 1) * 128;
            #pragma unroll
            for (int t = 0; t < NT_W; ++t) {
                int tg = t0 + t;
                int nb = tg * 16 + ((lane >> 4) << 2);
                if (tg < NT_TOT) {
                    float4 bb = *(const float4*)(bias + nb);
                    f32x4 a = acc[rt][t];
                    ushort4 v;
                    v.x = __builtin_bit_cast(unsigned short, (__bf16)(a[0] + bb.x));
                    v.y = __builtin_bit_cast(unsigned short, (__bf16)(a[1] + bb.y));
                    v.z = __builtin_bit_cast(unsigned short, (__bf16)(a[2] + bb.z));
                    v.w = __builtin_bit_cast(unsigned short, (__bf16)(a[3] + bb.w));
                    *(ushort4*)(Cp + rowb + nb) = v;
                }
            }
        } else if (MODE == 4) {
            int m = (rt0 + rt) * 16 + (lane & 15);
            #pragma unroll
            for (int t = 0; t < NT_W; ++t) {
                int tg = t0 + t;
                if (tg < NT_TOT) {
                    int nb = tg * 16 + ((lane >> 4) << 2);
                    f32x4 a = acc[rt][t];
                    if (nb < 144) {
                        float4 bb = *(const float4*)(bias + nb);
                        float4 v = {a[0] + bb.x, a[1] + bb.y, a[2] + bb.z, a[3] + bb.w};
                        *(float4*)(C + (size_t)m * 144 + nb) = v;
                    } else {
                        int col = nb - 144;
                        if (col + 4 <= 72) {
                            float4 bb = *(const float4*)(bias2 + col);
                            float4 v = {a[0] + bb.x, a[1] + bb.y, a[2] + bb.z, a[3] + bb.w};
                            *(float4*)(C2 + (size_t)m * 72 + col) = v;
                        }
                    }
                }
            }
        } else {
            int m4 = (rt0 + rt) * 16 + ((lane >> 4) << 2);
            int b = m4 >> 12, hw = m4 & 4095;
            #pragma unroll
            for (int t = 0; t < NT_W; ++t) {
                int tg = t0 + t;
                if (tg < NT_TOT) {
                    int n = tg * 16 + (lane & 15);
                    float bb = bias[n];
                    f32x4 a = acc[rt][t];
                    float4 v = {a[0] + bb, a[1] + bb, a[2] + bb, a[3] + bb};
                    *(float4*)(C + (((size_t)(b * 128 + n)) << 12) + hw) = v;
                }
            }
        }
    }
}

// ---------------------------------------------------------------------------
// K6: DCNv3 core v5. thread = (pos, g), 16 channels. grid 1024, block 256.
// bf16 xpad gathers (2x uint4 = 16ch per corner), clamped addressing.
// Softmax once per (pos,g). Output packed as fc1 hi/lo A-frags.
// ---------------------------------------------------------------------------
__global__ __launch_bounds__(256) void k_dcn(
    const unsigned short* __restrict__ xpad, const float* __restrict__ offs,
    const float* __restrict__ msk, unsigned short* __restrict__ dcnf)
{
    int u = blockIdx.x * 256 + threadIdx.x;  // 32768*8
    int g = u & 7;
    int pos = u >> 3;
    int b = pos >> 12, hw = pos & 4095, h = hw >> 6, w = hw & 63;

    const float* ml = msk + (size_t)pos * 72 + g * 9;
    float e[9];
    float mx = -1e30f;
    #pragma unroll
    for (int p = 0; p < 9; ++p) { e[p] = ml[p]; mx = fmaxf(mx, e[p]); }
    float ssum = 0.f;
    #pragma unroll
    for (int p = 0; p < 9; ++p) { e[p] = __expf(e[p] - mx); ssum += e[p]; }
    float inv = 1.0f / ssum;

    const float2* ob2 = (const float2*)(offs + (size_t)pos * 144 + g * 18);
    const unsigned short* xb = xpad + (size_t)b * 557568 + g * 16;  // 66*66*128/b

    float acc[16];
    #pragma unroll
    for (int i = 0; i < 16; ++i) acc[i] = 0.f;

    #pragma unroll
    for (int p = 0; p < 9; ++p) {
        float2 d = ob2[p];
        float px = (float)(w + (p % 3)) + d.x;   // padded-grid coords
        float py = (float)(h + (p / 3)) + d.y;
        float x0f = floorf(px), y0f = floorf(py);
        float wx = px - x0f, wy = py - y0f;
        int ix = (int)x0f, iy = (int)y0f;
        int ix0 = max(min(ix, 65), 0),     ix1 = max(min(ix + 1, 65), 0);
        int iy0 = max(min(iy, 65), 0),     iy1 = max(min(iy + 1, 65), 0);
        int r0 = iy0 * 66, r1 = iy1 * 66;

        float mp  = e[p] * inv;
        float w11 = wy * wx * mp;
        float w10 = wy * mp - w11;
        float w01 = wx * mp - w11;
        float w00 = mp - w01 - w10 - w11;

        const unsigned short* c00 = xb + (size_t)(r0 + ix0) * 128;
        const unsigned short* c01 = xb + (size_t)(r0 + ix1) * 128;
        const unsigned short* c10 = xb + (size_t)(r1 + ix0) * 128;
        const unsigned short* c11 = xb + (size_t)(r1 + ix1) * 128;

        uint4 a00 = *(const uint4*)(c00), b00 = *(const uint4*)(c00 + 8);
        uint4 a01 = *(const uint4*)(c01), b01 = *(const uint4*)(c01 + 8);
        uint4 a10 = *(const uint4*)(c10), b10 = *(const uint4*)(c10 + 8);
        uint4 a11 = *(const uint4*)(c11), b11 = *(const uint4*)(c11 + 8);

        ufma(acc,     a00, w00); ufma(acc + 8, b00, w00);
        ufma(acc,     a01, w01); ufma(acc + 8, b01, w01);
        ufma(acc,     a10, w10); ufma(acc + 8, b10, w10);
        ufma(acc,     a11, w11); ufma(acc + 8, b11, w11);
    }

    // pack 16 channels as two hi/lo frag groups
    int rt = pos >> 4, kc = g >> 1;
    int lp0 = (pos & 15) + (g & 1) * 32;
    size_t fb = ((size_t)rt * 4 + kc) * 1024 + (size_t)lp0 * 8;
    uint4 hiA, loA, hiB, loB;
    pack8(acc, hiA, loA);
    pack8(acc + 8, hiB, loB);
    *(uint4*)(dcnf + fb)             = hiA;
    *(uint4*)(dcnf + fb + 512)       = loA;
    *(uint4*)(dcnf + fb + 128)       = hiB;   // lp0+16
    *(uint4*)(dcnf + fb + 128 + 512) = loB;
}

// ---------------------------------------------------------------------------
extern "C" void kernel_launch(void* const* d_in, const int* in_sizes, int n_in,
                              void* d_out, int out_size, void* d_ws, size_t ws_size,
                              hipStream_t stream)
{
    const float* inp   = (const float*)d_in[0];
    const float* wproj = (const float*)d_in[1];
    const float* bproj = (const float*)d_in[2];
    const float* dww   = (const float*)d_in[3];
    const float* dwb   = (const float*)d_in[4];
    const float* gamma = (const float*)d_in[5];
    const float* beta  = (const float*)d_in[6];
    const float* woff  = (const float*)d_in[7];
    const float* boff  = (const float*)d_in[8];
    const float* wmask = (const float*)d_in[9];
    const float* bmask = (const float*)d_in[10];
    const float* wfc1  = (const float*)d_in[11];
    const float* bfc1  = (const float*)d_in[12];
    const float* wfc2  = (const float*)d_in[13];
    const float* bfc2  = (const float*)d_in[14];
    float* out = (float*)d_out;
    float* ws  = (float*)d_ws;

    // Region P: xpad (bf16) + offs; later hdnf (fc1 out frags)
    unsigned short* xpad = (unsigned short*)ws;          // 4,460,544 ush = 2,230,272 f
    float* offs = ws + 2230272;                          // 4,718,592 f -> ends 6,948,864
    unsigned short* hdnf = (unsigned short*)ws;          // 16,777,216 ush [fc1..fc2]
    // Region A [9179136, ...): time-shared
    float* ydw            = ws + 9179136;                // 4,194,304 f [dwconv..bngelu]
    unsigned short* inpf  = (unsigned short*)(ws + 9179136);   // hi-only [aprep..proj]
    unsigned short* dcnf  = (unsigned short*)(ws + 9179136);   // hi/lo [dcn..fc1]
    unsigned short* x1f   = (unsigned short*)(ws + 13373440);  // hi-only [bngelu..offmask]
    // Rest
    float* msk  = ws + 17567744;                         // 2,359,296 f
    float* psum = ws + 19927040;                         // 65,536 f
    float* psq  = ws + 19992576;                         // 65,536 f
    float* scs  = ws + 20058112;                         // 128 f
    float* shs  = ws + 20058240;                         // 128 f
    unsigned short* wfr = (unsigned short*)(ws + 20058368);  // 176,128 ush

    unsigned short* wproj_f = wfr;            // hi-only, 16384
    unsigned short* womb_f  = wfr + 16384;    // hi-only combined, 28672
    unsigned short* wfc1_f  = wfr + 45056;    // hi/lo, 65536
    unsigned short* wfc2_f  = wfr + 110592;   // hi/lo, 65536

    k_wprep<<<216, 64, 0, stream>>>(wproj, woff, wmask, wfc1, wfc2, wfr);
    k_aprep<<<2048, 256, 0, stream>>>(inp, inpf);
    k_border<<<130, 256, 0, stream>>>(xpad);
    k_fgemm<128,  8, 2, 3, 128, 1><<<dim3(256, 4), 256, 0, stream>>>(inpf, wproj_f, bproj, (float*)xpad, 0, nullptr, nullptr, nullptr);
    k_dwconv<<<512, 256, 0, stream>>>(inp, dww, dwb, ydw, psum, psq);
    k_bnstats<<<128, 256, 0, stream>>>(psum, psq, gamma, beta, scs, shs);
    k_bngelu<<<2048, 256, 0, stream>>>(ydw, scs, shs, x1f);
    k_fgemm<128, 14, 4, 4, 224, 1><<<dim3(256, 4), 256, 0, stream>>>(x1f, womb_f, boff, offs, 144, nullptr, bmask, msk);
    k_dcn<<<1024, 256, 0, stream>>>(xpad, offs, msk, dcnf);
    k_fgemm<128, 16, 4, 1, 256, 3><<<dim3(256, 4), 256, 0, stream>>>(dcnf, wfc1_f, bfc1, nullptr, 0, hdnf, nullptr, nullptr);
    k_fgemm<256,  8, 2, 2, 128, 3><<<dim3(256, 4), 256, 0, stream>>>(hdnf, wfc2_f, bfc2, out, 0, nullptr, nullptr, nullptr);
}

// Round 9
// 121.250 us; speedup vs baseline: 1.3986x; 1.0704x over previous
//
#include <hip/hip_runtime.h>
#include <math.h>

#define NPOS  32768      // B*H*W
#define CDIM  128
#define HS    64
#define WSZ   64

typedef __bf16 bf8_t  __attribute__((ext_vector_type(8)));
typedef float  f32x4  __attribute__((ext_vector_type(4)));

__device__ __forceinline__ float gelu_exact(float x) {
    return 0.5f * x * (1.0f + erff(x * 0.70710678118654752f));
}

__device__ __forceinline__ void hilo(float v, unsigned& h, unsigned& l) {
    __bf16 hb = (__bf16)v;
    h = (unsigned)__builtin_bit_cast(unsigned short, hb);
    __bf16 lb = (__bf16)(v - (float)hb);
    l = (unsigned)__builtin_bit_cast(unsigned short, lb);
}

__device__ __forceinline__ uint4 pack8hi(const float* v) {
    unsigned hh[8];
    #pragma unroll
    for (int i = 0; i < 8; ++i)
        hh[i] = (unsigned)__builtin_bit_cast(unsigned short, (__bf16)v[i]);
    return make_uint4(hh[0] | (hh[1] << 16), hh[2] | (hh[3] << 16),
                      hh[4] | (hh[5] << 16), hh[6] | (hh[7] << 16));
}

__device__ __forceinline__ float bfd(unsigned u) {        // low 16 bits as bf16
    return __builtin_bit_cast(float, u << 16);
}

// unpack uint4 (8 bf16) and fma into acc[8] with weight
__device__ __forceinline__ void ufma(float* acc, uint4 c, float wgt) {
    const unsigned* cc = (const unsigned*)&c;
    #pragma unroll
    for (int j = 0; j < 4; ++j) {
        acc[2 * j]     += __builtin_bit_cast(float, cc[j] << 16) * wgt;
        acc[2 * j + 1] += __builtin_bit_cast(float, cc[j] & 0xFFFF0000u) * wgt;
    }
}

// ---------------------------------------------------------------------------
// A-frag layouts (K=KC*32):
//  hi/lo buffers: block(rt,kc) = 1024 ush (hi 512 | lo 512)
//  hi-only buffers: block(rt,kc) = 512 ush
//  elem: lane*8 + i, lane = (row%16) + ((k%32)/8)*16, i = k%8
// ---------------------------------------------------------------------------

// ---------------------------------------------------------------------------
// K_prep (merged): blocks [0,2048) aprep: inp -> hi-only frags
//                  [2048,2178) border: zero 1-px ring of bf16 xpad
//                  [2178,2232) wprep: weights -> frag bf16
// ---------------------------------------------------------------------------
__global__ __launch_bounds__(256) void k_prep(
    const float* __restrict__ inp, unsigned short* __restrict__ inpf,
    unsigned short* __restrict__ xpad,
    const float* __restrict__ w0, const float* __restrict__ w1,
    const float* __restrict__ w2, const float* __restrict__ w3,
    const float* __restrict__ w4, unsigned short* __restrict__ wb)
{
    int bid = blockIdx.x, tid = threadIdx.x;
    if (bid < 2048) {
        int idx = bid * 256 + tid;                  // 32768*16
        int r = idx >> 4, k8 = (idx & 15) * 8;
        float t[8];
        *(float4*)(t)     = *(const float4*)(inp + (size_t)r * 128 + k8);
        *(float4*)(t + 4) = *(const float4*)(inp + (size_t)r * 128 + k8 + 4);
        uint4 hi = pack8hi(t);
        int rt = r >> 4, kc = k8 >> 5, lp = (r & 15) + ((k8 & 31) >> 3) * 16;
        size_t base = ((size_t)rt * 4 + kc) * 512 + lp * 8;
        *(uint4*)(inpf + base) = hi;
    } else if (bid < 2178) {
        int idx = (bid - 2048) * 256 + tid;         // 2080 cells * 16
        if (idx < 33280) {
            int c8 = (idx & 15) * 8;
            int cell = idx >> 4;
            int b = cell / 260, r = cell % 260;
            int h, w;
            if (r < 66)       { h = 0;  w = r; }
            else if (r < 132) { h = 65; w = r - 66; }
            else { int rr = r - 132; h = 1 + (rr >> 1); w = (rr & 1) * 65; }
            size_t o = (((size_t)b * 66 + h) * 66 + w) * 128 + c8;
            *(uint4*)(xpad + o) = make_uint4(0u, 0u, 0u, 0u);
        }
    } else {
        int sub = (bid - 2178) * 4 + (tid >> 6);    // 0..215
        int lane = tid & 63;
        int NT, K, local; unsigned short* out; bool hl; bool comb = false;
        const float* W = nullptr; int N = 0;
        if (sub < 32)       { NT = 8;  K = 128; out = wb;          local = sub;       hl = false; W = w0; N = 128; }
        else if (sub < 88)  { NT = 14; K = 128; out = wb + 16384;  local = sub - 32;  hl = false; comb = true; }
        else if (sub < 152) { NT = 16; K = 128; out = wb + 45056;  local = sub - 88;  hl = true;  W = w3; N = 256; }
        else                { NT = 8;  K = 256; out = wb + 110592; local = sub - 152; hl = true;  W = w4; N = 128; }
        int KC = K / 32;
        int unit = KC * NT * 512;
        int kc = local / NT, t = local % NT;
        int nt = t * 16 + (lane & 15);
        const float* Wp = W; int n = nt, Nv = N;
        if (comb) {
            if (t < 9) { Wp = w1; n = nt;       Nv = 144; }
            else       { Wp = w2; n = nt - 144; Nv = 72;  }
        }
        int kb = kc * 32 + (lane >> 4) * 8;
        size_t base = ((size_t)local * 64 + lane) * 8;
        #pragma unroll
        for (int i = 0; i < 8; ++i) {
            float v = (n < Nv) ? Wp[(size_t)n * K + kb + i] : 0.f;
            __bf16 h = (__bf16)v;
            out[base + i] = __builtin_bit_cast(unsigned short, h);
            if (hl) {
                __bf16 l = (__bf16)(v - (float)h);
                out[unit + base + i] = __builtin_bit_cast(unsigned short, l);
            }
        }
    }
}

// ---------------------------------------------------------------------------
// K1: depthwise 3x3 conv (NHWC) + per-block partial BN sums
// ---------------------------------------------------------------------------
__global__ __launch_bounds__(256) void k_dwconv(
    const float* __restrict__ inp, const float* __restrict__ dww,
    const float* __restrict__ dwb, float* __restrict__ ydw,
    float* __restrict__ psum, float* __restrict__ psq)
{
    int blk = blockIdx.x;            // b*64 + h
    int b = blk >> 6, h = blk & 63;
    int tid = threadIdx.x;
    int c4 = (tid & 31) * 4;
    int wg = tid >> 5;               // 0..7

    float wreg[4][9];
    #pragma unroll
    for (int cc = 0; cc < 4; ++cc)
        #pragma unroll
        for (int p = 0; p < 9; ++p)
            wreg[cc][p] = dww[(c4 + cc) * 9 + p];
    float bia[4];
    #pragma unroll
    for (int cc = 0; cc < 4; ++cc) bia[cc] = dwb[c4 + cc];

    float s4[4] = {0,0,0,0}, q4[4] = {0,0,0,0};
    const float* ibase = inp + (size_t)(b << 12) * CDIM;

    for (int i = 0; i < 8; ++i) {
        int w = wg + i * 8;
        float acc[4] = {bia[0], bia[1], bia[2], bia[3]};
        #pragma unroll
        for (int ky = 0; ky < 3; ++ky) {
            int yy = h + ky - 1;
            if (yy < 0 || yy >= HS) continue;
            #pragma unroll
            for (int kx = 0; kx < 3; ++kx) {
                int xx = w + kx - 1;
                if (xx < 0 || xx >= WSZ) continue;
                float4 v = *(const float4*)(ibase + (size_t)(yy * 64 + xx) * CDIM + c4);
                int p = ky * 3 + kx;
                acc[0] += v.x * wreg[0][p];
                acc[1] += v.y * wreg[1][p];
                acc[2] += v.z * wreg[2][p];
                acc[3] += v.w * wreg[3][p];
            }
        }
        float4 o = {acc[0], acc[1], acc[2], acc[3]};
        *(float4*)(ydw + ((size_t)(b << 12) + h * 64 + w) * CDIM + c4) = o;
        #pragma unroll
        for (int cc = 0; cc < 4; ++cc) { s4[cc] += acc[cc]; q4[cc] += acc[cc] * acc[cc]; }
    }

    __shared__ float ls[8][128], lq[8][128];
    #pragma unroll
    for (int cc = 0; cc < 4; ++cc) { ls[wg][c4 + cc] = s4[cc]; lq[wg][c4 + cc] = q4[cc]; }
    __syncthreads();
    if (tid < 128) {
        float s = 0.f, q = 0.f;
        #pragma unroll
        for (int r = 0; r < 8; ++r) { s += ls[r][tid]; q += lq[r][tid]; }
        psum[blk * 128 + tid] = s;
        psq [blk * 128 + tid] = q;
    }
}

// ---------------------------------------------------------------------------
// K2: finalize BN stats -> scale/shift per channel.
// ---------------------------------------------------------------------------
__global__ __launch_bounds__(256) void k_bnstats(
    const float* __restrict__ psum, const float* __restrict__ psq,
    const float* __restrict__ gamma, const float* __restrict__ beta,
    float* __restrict__ sc, float* __restrict__ sh)
{
    int c = blockIdx.x;
    int t = threadIdx.x;
    float s = psum[t * 128 + c] + psum[(t + 256) * 128 + c];
    float q = psq [t * 128 + c] + psq [(t + 256) * 128 + c];
    __shared__ float rs[256], rq[256];
    rs[t] = s; rq[t] = q; __syncthreads();
    for (int off = 128; off > 0; off >>= 1) {
        if (t < off) { rs[t] += rs[t + off]; rq[t] += rq[t + off]; }
        __syncthreads();
    }
    if (t == 0) {
        float mean = rs[0] * (1.0f / 32768.0f);
        float var  = rq[0] * (1.0f / 32768.0f) - mean * mean;
        float scale = gamma[c] * rsqrtf(var + 1e-5f);
        sc[c] = scale;
        sh[c] = beta[c] - mean * scale;
    }
}

// ---------------------------------------------------------------------------
// K3: BN + exact GELU, ydw (fp32) -> x1 hi-only frags. grid 2048, block 256.
// ---------------------------------------------------------------------------
__global__ __launch_bounds__(256) void k_bngelu(
    const float* __restrict__ ydw, const float* __restrict__ sc,
    const float* __restrict__ sh, unsigned short* __restrict__ dst)
{
    int idx = blockIdx.x * 256 + threadIdx.x;   // 32768*16
    int r = idx >> 4, k8 = (idx & 15) * 8;
    float t[8];
    *(float4*)(t)     = *(const float4*)(ydw + (size_t)r * 128 + k8);
    *(float4*)(t + 4) = *(const float4*)(ydw + (size_t)r * 128 + k8 + 4);
    float s[8], h[8];
    *(float4*)(s)     = *(const float4*)(sc + k8);
    *(float4*)(s + 4) = *(const float4*)(sc + k8 + 4);
    *(float4*)(h)     = *(const float4*)(sh + k8);
    *(float4*)(h + 4) = *(const float4*)(sh + k8 + 4);
    #pragma unroll
    for (int i = 0; i < 8; ++i) t[i] = gelu_exact(t[i] * s[i] + h[i]);
    uint4 hi = pack8hi(t);
    int rt = r >> 4, kc = k8 >> 5, lp = (r & 15) + ((k8 & 31) >> 3) * 16;
    size_t base = ((size_t)rt * 4 + kc) * 512 + lp * 8;
    *(uint4*)(dst + base) = hi;
}

// ---------------------------------------------------------------------------
// Frag-stream MFMA GEMM.
// ALO/WLO: whether A / W carry a lo (bf16 residual) stream.
// MODE 0: fp32 row-major + bias. MODE 1: bias+GELU -> hi-only frag out.
// MODE 2: NCHW transposed fp32 store. MODE 3: bf16 padded [b][66][66][128].
// MODE 4: bf16 split store: tiles 0..8 -> offs (ld 144), 9..13 -> msk (ld 72).
// ---------------------------------------------------------------------------
template<int KDIM, int NT_TOT, int NT_W, int MODE, int NV, int ALO, int WLO>
__global__ __launch_bounds__(256) void k_fgemm(
    const unsigned short* __restrict__ AF, const unsigned short* __restrict__ WF,
    const float* __restrict__ bias, float* __restrict__ C, int ldc,
    unsigned short* __restrict__ OF, const float* __restrict__ bias2,
    float* __restrict__ C2)
{
    constexpr int KC = KDIM / 32;
    constexpr int ABLK = ALO ? 128 : 64;   // bf8 units per (rt,kc) block
    int tid = threadIdx.x;
    int lane = tid & 63, w = tid >> 6;
    int rt0 = blockIdx.x * 8 + w * 2;      // 2 rowtiles per wave
    int t0 = blockIdx.y * NT_W;            // n-tile chunk base

    f32x4 acc[2][NT_W];
    #pragma unroll
    for (int rt = 0; rt < 2; ++rt)
        #pragma unroll
        for (int t = 0; t < NT_W; ++t) acc[rt][t] = (f32x4){0.f, 0.f, 0.f, 0.f};

    const bf8_t* Ab0 = (const bf8_t*)AF + (size_t)rt0 * KC * ABLK + lane;
    const bf8_t* Ab1 = Ab0 + KC * ABLK;
    const bf8_t* WHp = (const bf8_t*)WF + lane;
    const bf8_t* WLp = WHp + KC * NT_TOT * 64;

    #pragma unroll
    for (int kc = 0; kc < KC; ++kc) {
        bf8_t a0h = Ab0[kc * ABLK];
        bf8_t a1h = Ab1[kc * ABLK];
        bf8_t a0l, a1l;
        if (ALO) { a0l = Ab0[kc * ABLK + 64]; a1l = Ab1[kc * ABLK + 64]; }
        #pragma unroll
        for (int t = 0; t < NT_W; ++t) {
            int tg = t0 + t;
            if (tg < NT_TOT) {
                bf8_t wh = WHp[(kc * NT_TOT + tg) * 64];
                if (MODE == 2) {
                    acc[0][t] = __builtin_amdgcn_mfma_f32_16x16x32_bf16(a0h, wh, acc[0][t], 0, 0, 0);
                    acc[1][t] = __builtin_amdgcn_mfma_f32_16x16x32_bf16(a1h, wh, acc[1][t], 0, 0, 0);
                    if (WLO) {
                        bf8_t wl = WLp[(kc * NT_TOT + tg) * 64];
                        acc[0][t] = __builtin_amdgcn_mfma_f32_16x16x32_bf16(a0h, wl, acc[0][t], 0, 0, 0);
                        acc[1][t] = __builtin_amdgcn_mfma_f32_16x16x32_bf16(a1h, wl, acc[1][t], 0, 0, 0);
                    }
                    if (ALO) {
                        acc[0][t] = __builtin_amdgcn_mfma_f32_16x16x32_bf16(a0l, wh, acc[0][t], 0, 0, 0);
                        acc[1][t] = __builtin_amdgcn_mfma_f32_16x16x32_bf16(a1l, wh, acc[1][t], 0, 0, 0);
                    }
                } else {
                    acc[0][t] = __builtin_amdgcn_mfma_f32_16x16x32_bf16(wh, a0h, acc[0][t], 0, 0, 0);
                    acc[1][t] = __builtin_amdgcn_mfma_f32_16x16x32_bf16(wh, a1h, acc[1][t], 0, 0, 0);
                    if (WLO) {
                        bf8_t wl = WLp[(kc * NT_TOT + tg) * 64];
                        acc[0][t] = __builtin_amdgcn_mfma_f32_16x16x32_bf16(wl, a0h, acc[0][t], 0, 0, 0);
                        acc[1][t] = __builtin_amdgcn_mfma_f32_16x16x32_bf16(wl, a1h, acc[1][t], 0, 0, 0);
                    }
                    if (ALO) {
                        acc[0][t] = __builtin_amdgcn_mfma_f32_16x16x32_bf16(wh, a0l, acc[0][t], 0, 0, 0);
                        acc[1][t] = __builtin_amdgcn_mfma_f32_16x16x32_bf16(wh, a1l, acc[1][t], 0, 0, 0);
                    }
                }
            }
        }
    }

    #pragma unroll
    for (int rt = 0; rt < 2; ++rt) {
        if (MODE == 0) {
            int m = (rt0 + rt) * 16 + (lane & 15);
            #pragma unroll
            for (int t = 0; t < NT_W; ++t) {
                int tg = t0 + t;
                int nb = tg * 16 + ((lane >> 4) << 2);
                if (tg < NT_TOT && nb + 4 <= NV) {
                    float4 bb = *(const float4*)(bias + nb);
                    f32x4 a = acc[rt][t];
                    float4 v = {a[0] + bb.x, a[1] + bb.y, a[2] + bb.z, a[3] + bb.w};
                    *(float4*)(C + (size_t)m * ldc + nb) = v;
                }
            }
        } else if (MODE == 1) {
            int m = (rt0 + rt) * 16 + (lane & 15);
            #pragma unroll
            for (int t = 0; t < NT_W; ++t) {
                int tg = t0 + t;
                if (tg < NT_TOT) {
                    int nb = tg * 16 + ((lane >> 4) << 2);
                    float4 bb = *(const float4*)(bias + nb);
                    f32x4 a = acc[rt][t];
                    float v[4];
                    v[0] = gelu_exact(a[0] + bb.x); v[1] = gelu_exact(a[1] + bb.y);
                    v[2] = gelu_exact(a[2] + bb.z); v[3] = gelu_exact(a[3] + bb.w);
                    unsigned hh[4];
                    #pragma unroll
                    for (int i = 0; i < 4; ++i)
                        hh[i] = (unsigned)__builtin_bit_cast(unsigned short, (__bf16)v[i]);
                    uint2 hi = make_uint2(hh[0] | (hh[1] << 16), hh[2] | (hh[3] << 16));
                    int kco = nb >> 5, lp = (m & 15) + ((nb & 31) >> 3) * 16;
                    size_t fb = ((size_t)(rt0 + rt) * (NV / 32) + kco) * 512 + lp * 8 + (nb & 7);
                    *(uint2*)(OF + fb) = hi;
                }
            }
        } else if (MODE == 3) {
            // bf16 store into zero-padded [b][66][66][128]
            unsigned short* Cp = (unsigned short*)C;
            int m = (rt0 + rt) * 16 + (lane & 15);
            int bb_ = m >> 12, hwm = m & 4095;
            size_t rowb = (((size_t)bb_ * 66 + (hwm >> 6) + 1) * 66 + (hwm & 63) + 1) * 128;
            #pragma unroll
            for (int t = 0; t < NT_W; ++t) {
                int tg = t0 + t;
                int nb = tg * 16 + ((lane >> 4) << 2);
                if (tg < NT_TOT) {
                    float4 bb = *(const float4*)(bias + nb);
                    f32x4 a = acc[rt][t];
                    ushort4 v;
                    v.x = __builtin_bit_cast(unsigned short, (__bf16)(a[0] + bb.x));
                    v.y = __builtin_bit_cast(unsigned short, (__bf16)(a[1] + bb.y));
                    v.z = __builtin_bit_cast(unsigned short, (__bf16)(a[2] + bb.z));
                    v.w = __builtin_bit_cast(unsigned short, (__bf16)(a[3] + bb.w));
                    *(ushort4*)(Cp + rowb + nb) = v;
                }
            }
        } else if (MODE == 4) {
            // bf16 split store: offs (C, ld 144) and msk (C2, ld 72)
            unsigned short* Co = (unsigned short*)C;
            unsigned short* Cm = (unsigned short*)C2;
            int m = (rt0 + rt) * 16 + (lane & 15);
            #pragma unroll
            for (int t = 0; t < NT_W; ++t) {
                int tg = t0 + t;
                if (tg < NT_TOT) {
                    int nb = tg * 16 + ((lane >> 4) << 2);
                    f32x4 a = acc[rt][t];
                    if (nb < 144) {
                        float4 bb = *(const float4*)(bias + nb);
                        ushort4 v;
                        v.x = __builtin_bit_cast(unsigned short, (__bf16)(a[0] + bb.x));
                        v.y = __builtin_bit_cast(unsigned short, (__bf16)(a[1] + bb.y));
                        v.z = __builtin_bit_cast(unsigned short, (__bf16)(a[2] + bb.z));
                        v.w = __builtin_bit_cast(unsigned short, (__bf16)(a[3] + bb.w));
                        *(ushort4*)(Co + (size_t)m * 144 + nb) = v;
                    } else {
                        int col = nb - 144;
                        if (col + 4 <= 72) {
                            float4 bb = *(const float4*)(bias2 + col);
                            ushort4 v;
                            v.x = __builtin_bit_cast(unsigned short, (__bf16)(a[0] + bb.x));
                            v.y = __builtin_bit_cast(unsigned short, (__bf16)(a[1] + bb.y));
                            v.z = __builtin_bit_cast(unsigned short, (__bf16)(a[2] + bb.z));
                            v.w = __builtin_bit_cast(unsigned short, (__bf16)(a[3] + bb.w));
                            *(ushort4*)(Cm + (size_t)m * 72 + col) = v;
                        }
                    }
                }
            }
        } else {
            int m4 = (rt0 + rt) * 16 + ((lane >> 4) << 2);
            int b = m4 >> 12, hw = m4 & 4095;
            #pragma unroll
            for (int t = 0; t < NT_W; ++t) {
                int tg = t0 + t;
                if (tg < NT_TOT) {
                    int n = tg * 16 + (lane & 15);
                    float bb = bias[n];
                    f32x4 a = acc[rt][t];
                    float4 v = {a[0] + bb, a[1] + bb, a[2] + bb, a[3] + bb};
                    *(float4*)(C + (((size_t)(b * 128 + n)) << 12) + hw) = v;
                }
            }
        }
    }
}

// ---------------------------------------------------------------------------
// K6: DCNv3 core v6. thread = (pos, g), 16 channels. grid 1024, block 256.
// bf16 xpad gathers, bf16 offs/msk inputs, clamped addressing.
// Softmax once per (pos,g). Output packed as fc1 hi-only A-frags.
// ---------------------------------------------------------------------------
__global__ __launch_bounds__(256) void k_dcn(
    const unsigned short* __restrict__ xpad, const unsigned short* __restrict__ offs,
    const unsigned short* __restrict__ msk, unsigned short* __restrict__ dcnf)
{
    int u = blockIdx.x * 256 + threadIdx.x;  // 32768*8
    int g = u & 7;
    int pos = u >> 3;
    int b = pos >> 12, hw = pos & 4095, h = hw >> 6, w = hw & 63;

    const unsigned short* ml = msk + (size_t)pos * 72 + g * 9;
    float e[9];
    float mx = -1e30f;
    #pragma unroll
    for (int p = 0; p < 9; ++p) { e[p] = bfd((unsigned)ml[p]); mx = fmaxf(mx, e[p]); }
    float ssum = 0.f;
    #pragma unroll
    for (int p = 0; p < 9; ++p) { e[p] = __expf(e[p] - mx); ssum += e[p]; }
    float inv = 1.0f / ssum;

    const unsigned short* ob = offs + (size_t)pos * 144 + g * 18;
    const unsigned short* xb = xpad + (size_t)b * 557568 + g * 16;  // 66*66*128/b

    float acc[16];
    #pragma unroll
    for (int i = 0; i < 16; ++i) acc[i] = 0.f;

    #pragma unroll
    for (int p = 0; p < 9; ++p) {
        unsigned dpair = *(const unsigned*)(ob + p * 2);
        float dx = bfd(dpair);
        float dy = __builtin_bit_cast(float, dpair & 0xFFFF0000u);
        float px = (float)(w + (p % 3)) + dx;   // padded-grid coords
        float py = (float)(h + (p / 3)) + dy;
        float x0f = floorf(px), y0f = floorf(py);
        float wx = px - x0f, wy = py - y0f;
        int ix = (int)x0f, iy = (int)y0f;
        int ix0 = max(min(ix, 65), 0),     ix1 = max(min(ix + 1, 65), 0);
        int iy0 = max(min(iy, 65), 0),     iy1 = max(min(iy + 1, 65), 0);
        int r0 = iy0 * 66, r1 = iy1 * 66;

        float mp  = e[p] * inv;
        float w11 = wy * wx * mp;
        float w10 = wy * mp - w11;
        float w01 = wx * mp - w11;
        float w00 = mp - w01 - w10 - w11;

        const unsigned short* c00 = xb + (size_t)(r0 + ix0) * 128;
        const unsigned short* c01 = xb + (size_t)(r0 + ix1) * 128;
        const unsigned short* c10 = xb + (size_t)(r1 + ix0) * 128;
        const unsigned short* c11 = xb + (size_t)(r1 + ix1) * 128;

        uint4 a00 = *(const uint4*)(c00), b00 = *(const uint4*)(c00 + 8);
        uint4 a01 = *(const uint4*)(c01), b01 = *(const uint4*)(c01 + 8);
        uint4 a10 = *(const uint4*)(c10), b10 = *(const uint4*)(c10 + 8);
        uint4 a11 = *(const uint4*)(c11), b11 = *(const uint4*)(c11 + 8);

        ufma(acc,     a00, w00); ufma(acc + 8, b00, w00);
        ufma(acc,     a01, w01); ufma(acc + 8, b01, w01);
        ufma(acc,     a10, w10); ufma(acc + 8, b10, w10);
        ufma(acc,     a11, w11); ufma(acc + 8, b11, w11);
    }

    // pack 16 channels as two hi-only frag groups
    int rt = pos >> 4, kc = g >> 1;
    int lp0 = (pos & 15) + (g & 1) * 32;
    size_t fb = ((size_t)rt * 4 + kc) * 512 + (size_t)lp0 * 8;
    uint4 hiA = pack8hi(acc);
    uint4 hiB = pack8hi(acc + 8);
    *(uint4*)(dcnf + fb)       = hiA;
    *(uint4*)(dcnf + fb + 128) = hiB;   // lp0+16
}

// ---------------------------------------------------------------------------
extern "C" void kernel_launch(void* const* d_in, const int* in_sizes, int n_in,
                              void* d_out, int out_size, void* d_ws, size_t ws_size,
                              hipStream_t stream)
{
    const float* inp   = (const float*)d_in[0];
    const float* wproj = (const float*)d_in[1];
    const float* bproj = (const float*)d_in[2];
    const float* dww   = (const float*)d_in[3];
    const float* dwb   = (const float*)d_in[4];
    const float* gamma = (const float*)d_in[5];
    const float* beta  = (const float*)d_in[6];
    const float* woff  = (const float*)d_in[7];
    const float* boff  = (const float*)d_in[8];
    const float* wmask = (const float*)d_in[9];
    const float* bmask = (const float*)d_in[10];
    const float* wfc1  = (const float*)d_in[11];
    const float* bfc1  = (const float*)d_in[12];
    const float* wfc2  = (const float*)d_in[13];
    const float* bfc2  = (const float*)d_in[14];
    float* out = (float*)d_out;
    float* ws  = (float*)d_ws;

    // Region P: xpad (bf16) + offs (bf16); later hdnf (fc1 hi-only frags)
    unsigned short* xpad = (unsigned short*)ws;          // 4,460,544 ush [proj..dcn]
    unsigned short* offs = (unsigned short*)(ws + 2230272); // 4,718,592 ush [offmask..dcn]
    unsigned short* hdnf = (unsigned short*)ws;          // 8,388,608 ush [fc1..fc2]
    // Region A: time-shared at ws+9179136
    float* ydw            = ws + 9179136;                // 4,194,304 f [dwconv..bngelu]
    unsigned short* inpf  = (unsigned short*)(ws + 9179136);   // 4,194,304 ush hi-only [prep..proj]
    unsigned short* dcnf  = (unsigned short*)(ws + 9179136);   // 4,194,304 ush hi-only [dcn..fc1]
    unsigned short* x1f   = (unsigned short*)(ws + 13373440);  // 4,194,304 ush hi-only [bngelu..offmask]
    // Rest
    unsigned short* msk = (unsigned short*)(ws + 17567744);  // 2,359,296 ush
    float* psum = ws + 19927040;                         // 65,536 f
    float* psq  = ws + 19992576;                         // 65,536 f
    float* scs  = ws + 20058112;                         // 128 f
    float* shs  = ws + 20058240;                         // 128 f
    unsigned short* wfr = (unsigned short*)(ws + 20058368);  // 176,128 ush

    unsigned short* wproj_f = wfr;            // hi-only, 16384
    unsigned short* womb_f  = wfr + 16384;    // hi-only combined, 28672
    unsigned short* wfc1_f  = wfr + 45056;    // hi/lo, 65536
    unsigned short* wfc2_f  = wfr + 110592;   // hi/lo, 65536

    k_prep<<<2232, 256, 0, stream>>>(inp, inpf, xpad, wproj, woff, wmask, wfc1, wfc2, wfr);
    k_fgemm<128,  8, 2, 3, 128, 0, 0><<<dim3(256, 4), 256, 0, stream>>>(inpf, wproj_f, bproj, (float*)xpad, 0, nullptr, nullptr, nullptr);
    k_dwconv<<<512, 256, 0, stream>>>(inp, dww, dwb, ydw, psum, psq);
    k_bnstats<<<128, 256, 0, stream>>>(psum, psq, gamma, beta, scs, shs);
    k_bngelu<<<2048, 256, 0, stream>>>(ydw, scs, shs, x1f);
    k_fgemm<128, 14, 4, 4, 224, 0, 0><<<dim3(256, 4), 256, 0, stream>>>(x1f, womb_f, boff, (float*)offs, 144, nullptr, bmask, (float*)msk);
    k_dcn<<<1024, 256, 0, stream>>>(xpad, offs, msk, dcnf);
    k_fgemm<128, 16, 4, 1, 256, 0, 1><<<dim3(256, 4), 256, 0, stream>>>(dcnf, wfc1_f, bfc1, nullptr, 0, hdnf, nullptr, nullptr);
    k_fgemm<256,  8, 4, 2, 128, 0, 1><<<dim3(256, 2), 256, 0, stream>>>(hdnf, wfc2_f, bfc2, out, 0, nullptr, nullptr, nullptr);
}

// Round 10
// 114.202 us; speedup vs baseline: 1.4849x; 1.0617x over previous
//
#include <hip/hip_runtime.h>
#include <math.h>

#define NPOS  32768      // B*H*W
#define CDIM  128
#define HS    64
#define WSZ   64

typedef __bf16 bf8_t  __attribute__((ext_vector_type(8)));
typedef float  f32x4  __attribute__((ext_vector_type(4)));

__device__ __forceinline__ float gelu_exact(float x) {
    return 0.5f * x * (1.0f + erff(x * 0.70710678118654752f));
}

__device__ __forceinline__ unsigned short bf16c(float v) {
    return __builtin_bit_cast(unsigned short, (__bf16)v);
}

__device__ __forceinline__ uint4 pack8hi(const float* v) {
    unsigned hh[8];
    #pragma unroll
    for (int i = 0; i < 8; ++i) hh[i] = (unsigned)bf16c(v[i]);
    return make_uint4(hh[0] | (hh[1] << 16), hh[2] | (hh[3] << 16),
                      hh[4] | (hh[5] << 16), hh[6] | (hh[7] << 16));
}

__device__ __forceinline__ float bfd(unsigned u) {        // low 16 bits as bf16
    return __builtin_bit_cast(float, u << 16);
}

// unpack uint4 (8 bf16) and fma into acc[8] with weight
__device__ __forceinline__ void ufma(float* acc, uint4 c, float wgt) {
    const unsigned* cc = (const unsigned*)&c;
    #pragma unroll
    for (int j = 0; j < 4; ++j) {
        acc[2 * j]     += __builtin_bit_cast(float, cc[j] << 16) * wgt;
        acc[2 * j + 1] += __builtin_bit_cast(float, cc[j] & 0xFFFF0000u) * wgt;
    }
}

// ---------------------------------------------------------------------------
// A-frag layouts (K=KC*32):
//  hi/lo buffers: block(rt,kc) = 1024 ush (hi 512 | lo 512)
//  hi-only buffers: block(rt,kc) = 512 ush
//  elem: lane*8 + i, lane = (row%16) + ((k%32)/8)*16, i = k%8
// ---------------------------------------------------------------------------

// ---------------------------------------------------------------------------
// prep body: blocks [0,2048) aprep: inp -> hi-only frags
//            [2048,2178) border: zero 1-px ring of bf16 xpad
//            [2178,2232) wprep: weights -> frag bf16
// ---------------------------------------------------------------------------
__device__ void prep_body(
    int bid, int tid,
    const float* __restrict__ inp, unsigned short* __restrict__ inpf,
    unsigned short* __restrict__ xpad,
    const float* __restrict__ w0, const float* __restrict__ w1,
    const float* __restrict__ w2, const float* __restrict__ w3,
    const float* __restrict__ w4, unsigned short* __restrict__ wb)
{
    if (bid < 2048) {
        int idx = bid * 256 + tid;                  // 32768*16
        int r = idx >> 4, k8 = (idx & 15) * 8;
        float t[8];
        *(float4*)(t)     = *(const float4*)(inp + (size_t)r * 128 + k8);
        *(float4*)(t + 4) = *(const float4*)(inp + (size_t)r * 128 + k8 + 4);
        uint4 hi = pack8hi(t);
        int rt = r >> 4, kc = k8 >> 5, lp = (r & 15) + ((k8 & 31) >> 3) * 16;
        size_t base = ((size_t)rt * 4 + kc) * 512 + lp * 8;
        *(uint4*)(inpf + base) = hi;
    } else if (bid < 2178) {
        int idx = (bid - 2048) * 256 + tid;         // 2080 cells * 16
        if (idx < 33280) {
            int c8 = (idx & 15) * 8;
            int cell = idx >> 4;
            int b = cell / 260, r = cell % 260;
            int h, w;
            if (r < 66)       { h = 0;  w = r; }
            else if (r < 132) { h = 65; w = r - 66; }
            else { int rr = r - 132; h = 1 + (rr >> 1); w = (rr & 1) * 65; }
            size_t o = (((size_t)b * 66 + h) * 66 + w) * 128 + c8;
            *(uint4*)(xpad + o) = make_uint4(0u, 0u, 0u, 0u);
        }
    } else {
        int sub = (bid - 2178) * 4 + (tid >> 6);    // 0..215
        int lane = tid & 63;
        int NT, K, local; unsigned short* out; bool hl; bool comb = false;
        const float* W = nullptr; int N = 0;
        if (sub < 32)       { NT = 8;  K = 128; out = wb;          local = sub;       hl = false; W = w0; N = 128; }
        else if (sub < 88)  { NT = 14; K = 128; out = wb + 16384;  local = sub - 32;  hl = false; comb = true; }
        else if (sub < 152) { NT = 16; K = 128; out = wb + 45056;  local = sub - 88;  hl = true;  W = w3; N = 256; }
        else                { NT = 8;  K = 256; out = wb + 110592; local = sub - 152; hl = true;  W = w4; N = 128; }
        int KC = K / 32;
        int unit = KC * NT * 512;
        int kc = local / NT, t = local % NT;
        int nt = t * 16 + (lane & 15);
        const float* Wp = W; int n = nt, Nv = N;
        if (comb) {
            if (t < 9) { Wp = w1; n = nt;       Nv = 144; }
            else       { Wp = w2; n = nt - 144; Nv = 72;  }
        }
        int kb = kc * 32 + (lane >> 4) * 8;
        size_t base = ((size_t)local * 64 + lane) * 8;
        #pragma unroll
        for (int i = 0; i < 8; ++i) {
            float v = (n < Nv) ? Wp[(size_t)n * K + kb + i] : 0.f;
            __bf16 h = (__bf16)v;
            out[base + i] = __builtin_bit_cast(unsigned short, h);
            if (hl) {
                __bf16 l = (__bf16)(v - (float)h);
                out[unit + base + i] = __builtin_bit_cast(unsigned short, l);
            }
        }
    }
}

// ---------------------------------------------------------------------------
// dwconv body: depthwise 3x3 (NHWC) -> bf16 ydw + partial BN sums (fp32)
// ---------------------------------------------------------------------------
__device__ void dwconv_body(
    int blk, int tid,
    const float* __restrict__ inp, const float* __restrict__ dww,
    const float* __restrict__ dwb, unsigned short* __restrict__ ydwb,
    float* __restrict__ psum, float* __restrict__ psq)
{
    int b = blk >> 6, h = blk & 63;
    int c4 = (tid & 31) * 4;
    int wg = tid >> 5;               // 0..7

    float wreg[4][9];
    #pragma unroll
    for (int cc = 0; cc < 4; ++cc)
        #pragma unroll
        for (int p = 0; p < 9; ++p)
            wreg[cc][p] = dww[(c4 + cc) * 9 + p];
    float bia[4];
    #pragma unroll
    for (int cc = 0; cc < 4; ++cc) bia[cc] = dwb[c4 + cc];

    float s4[4] = {0,0,0,0}, q4[4] = {0,0,0,0};
    const float* ibase = inp + (size_t)(b << 12) * CDIM;

    for (int i = 0; i < 8; ++i) {
        int w = wg + i * 8;
        float acc[4] = {bia[0], bia[1], bia[2], bia[3]};
        #pragma unroll
        for (int ky = 0; ky < 3; ++ky) {
            int yy = h + ky - 1;
            if (yy < 0 || yy >= HS) continue;
            #pragma unroll
            for (int kx = 0; kx < 3; ++kx) {
                int xx = w + kx - 1;
                if (xx < 0 || xx >= WSZ) continue;
                float4 v = *(const float4*)(ibase + (size_t)(yy * 64 + xx) * CDIM + c4);
                int p = ky * 3 + kx;
                acc[0] += v.x * wreg[0][p];
                acc[1] += v.y * wreg[1][p];
                acc[2] += v.z * wreg[2][p];
                acc[3] += v.w * wreg[3][p];
            }
        }
        ushort4 o;
        o.x = bf16c(acc[0]); o.y = bf16c(acc[1]);
        o.z = bf16c(acc[2]); o.w = bf16c(acc[3]);
        *(ushort4*)(ydwb + ((size_t)(b << 12) + h * 64 + w) * CDIM + c4) = o;
        #pragma unroll
        for (int cc = 0; cc < 4; ++cc) { s4[cc] += acc[cc]; q4[cc] += acc[cc] * acc[cc]; }
    }

    __shared__ float ls[8][128], lq[8][128];
    #pragma unroll
    for (int cc = 0; cc < 4; ++cc) { ls[wg][c4 + cc] = s4[cc]; lq[wg][c4 + cc] = q4[cc]; }
    __syncthreads();
    if (tid < 128) {
        float s = 0.f, q = 0.f;
        #pragma unroll
        for (int r = 0; r < 8; ++r) { s += ls[r][tid]; q += lq[r][tid]; }
        psum[blk * 128 + tid] = s;
        psq [blk * 128 + tid] = q;
    }
}

// K_pd: merged prep (2232 blocks) + dwconv (512 blocks). grid 2744.
__global__ __launch_bounds__(256) void k_pd(
    const float* __restrict__ inp, unsigned short* __restrict__ inpf,
    unsigned short* __restrict__ xpad,
    const float* __restrict__ w0, const float* __restrict__ w1,
    const float* __restrict__ w2, const float* __restrict__ w3,
    const float* __restrict__ w4, unsigned short* __restrict__ wb,
    const float* __restrict__ dww, const float* __restrict__ dwb,
    unsigned short* __restrict__ ydwb, float* __restrict__ psum,
    float* __restrict__ psq)
{
    int bid = blockIdx.x;
    if (bid < 2232) prep_body(bid, threadIdx.x, inp, inpf, xpad, w0, w1, w2, w3, w4, wb);
    else            dwconv_body(bid - 2232, threadIdx.x, inp, dww, dwb, ydwb, psum, psq);
}

// ---------------------------------------------------------------------------
// K2: finalize BN stats -> scale/shift per channel.
// ---------------------------------------------------------------------------
__global__ __launch_bounds__(256) void k_bnstats(
    const float* __restrict__ psum, const float* __restrict__ psq,
    const float* __restrict__ gamma, const float* __restrict__ beta,
    float* __restrict__ sc, float* __restrict__ sh)
{
    int c = blockIdx.x;
    int t = threadIdx.x;
    float s = psum[t * 128 + c] + psum[(t + 256) * 128 + c];
    float q = psq [t * 128 + c] + psq [(t + 256) * 128 + c];
    __shared__ float rs[256], rq[256];
    rs[t] = s; rq[t] = q; __syncthreads();
    for (int off = 128; off > 0; off >>= 1) {
        if (t < off) { rs[t] += rs[t + off]; rq[t] += rq[t + off]; }
        __syncthreads();
    }
    if (t == 0) {
        float mean = rs[0] * (1.0f / 32768.0f);
        float var  = rq[0] * (1.0f / 32768.0f) - mean * mean;
        float scale = gamma[c] * rsqrtf(var + 1e-5f);
        sc[c] = scale;
        sh[c] = beta[c] - mean * scale;
    }
}

// ---------------------------------------------------------------------------
// bngelu body: bf16 ydw -> BN + exact GELU -> x1 hi-only frags.
// ---------------------------------------------------------------------------
__device__ void bngelu_body(
    int bid, int tid,
    const unsigned short* __restrict__ ydwb, const float* __restrict__ sc,
    const float* __restrict__ sh, unsigned short* __restrict__ dst)
{
    int idx = bid * 256 + tid;   // 32768*16
    int r = idx >> 4, k8 = (idx & 15) * 8;
    uint4 yv = *(const uint4*)(ydwb + (size_t)r * 128 + k8);
    const unsigned* cc = (const unsigned*)&yv;
    float t[8];
    #pragma unroll
    for (int j = 0; j < 4; ++j) {
        t[2 * j]     = bfd(cc[j]);
        t[2 * j + 1] = __builtin_bit_cast(float, cc[j] & 0xFFFF0000u);
    }
    float s[8], h[8];
    *(float4*)(s)     = *(const float4*)(sc + k8);
    *(float4*)(s + 4) = *(const float4*)(sc + k8 + 4);
    *(float4*)(h)     = *(const float4*)(sh + k8);
    *(float4*)(h + 4) = *(const float4*)(sh + k8 + 4);
    #pragma unroll
    for (int i = 0; i < 8; ++i) t[i] = gelu_exact(t[i] * s[i] + h[i]);
    uint4 hi = pack8hi(t);
    int rt = r >> 4, kc = k8 >> 5, lp = (r & 15) + ((k8 & 31) >> 3) * 16;
    size_t base = ((size_t)rt * 4 + kc) * 512 + lp * 8;
    *(uint4*)(dst + base) = hi;
}

// ---------------------------------------------------------------------------
// Frag-stream MFMA GEMM body.
// ALO/WLO: whether A / W carry a lo (bf16 residual) stream.
// MODE 0: fp32 row-major + bias. MODE 1: bias+GELU -> hi-only frag out.
// MODE 2: NCHW transposed fp32 store. MODE 3: bf16 padded [b][66][66][128].
// MODE 4: bf16 split store: tiles 0..8 -> offs (ld 144), 9..13 -> msk (ld 72).
// ---------------------------------------------------------------------------
template<int KDIM, int NT_TOT, int NT_W, int MODE, int NV, int ALO, int WLO>
__device__ void fgemm_body(
    int bx, int by, int tid,
    const unsigned short* __restrict__ AF, const unsigned short* __restrict__ WF,
    const float* __restrict__ bias, float* __restrict__ C, int ldc,
    unsigned short* __restrict__ OF, const float* __restrict__ bias2,
    float* __restrict__ C2)
{
    constexpr int KC = KDIM / 32;
    constexpr int ABLK = ALO ? 128 : 64;   // bf8 units per (rt,kc) block
    int lane = tid & 63, w = tid >> 6;
    int rt0 = bx * 8 + w * 2;      // 2 rowtiles per wave
    int t0 = by * NT_W;            // n-tile chunk base

    f32x4 acc[2][NT_W];
    #pragma unroll
    for (int rt = 0; rt < 2; ++rt)
        #pragma unroll
        for (int t = 0; t < NT_W; ++t) acc[rt][t] = (f32x4){0.f, 0.f, 0.f, 0.f};

    const bf8_t* Ab0 = (const bf8_t*)AF + (size_t)rt0 * KC * ABLK + lane;
    const bf8_t* Ab1 = Ab0 + KC * ABLK;
    const bf8_t* WHp = (const bf8_t*)WF + lane;
    const bf8_t* WLp = WHp + KC * NT_TOT * 64;

    #pragma unroll
    for (int kc = 0; kc < KC; ++kc) {
        bf8_t a0h = Ab0[kc * ABLK];
        bf8_t a1h = Ab1[kc * ABLK];
        bf8_t a0l, a1l;
        if (ALO) { a0l = Ab0[kc * ABLK + 64]; a1l = Ab1[kc * ABLK + 64]; }
        #pragma unroll
        for (int t = 0; t < NT_W; ++t) {
            int tg = t0 + t;
            if (tg < NT_TOT) {
                bf8_t wh = WHp[(kc * NT_TOT + tg) * 64];
                if (MODE == 2) {
                    acc[0][t] = __builtin_amdgcn_mfma_f32_16x16x32_bf16(a0h, wh, acc[0][t], 0, 0, 0);
                    acc[1][t] = __builtin_amdgcn_mfma_f32_16x16x32_bf16(a1h, wh, acc[1][t], 0, 0, 0);
                    if (WLO) {
                        bf8_t wl = WLp[(kc * NT_TOT + tg) * 64];
                        acc[0][t] = __builtin_amdgcn_mfma_f32_16x16x32_bf16(a0h, wl, acc[0][t], 0, 0, 0);
                        acc[1][t] = __builtin_amdgcn_mfma_f32_16x16x32_bf16(a1h, wl, acc[1][t], 0, 0, 0);
                    }
                    if (ALO) {
                        acc[0][t] = __builtin_amdgcn_mfma_f32_16x16x32_bf16(a0l, wh, acc[0][t], 0, 0, 0);
                        acc[1][t] = __builtin_amdgcn_mfma_f32_16x16x32_bf16(a1l, wh, acc[1][t], 0, 0, 0);
                    }
                } else {
                    acc[0][t] = __builtin_amdgcn_mfma_f32_16x16x32_bf16(wh, a0h, acc[0][t], 0, 0, 0);
                    acc[1][t] = __builtin_amdgcn_mfma_f32_16x16x32_bf16(wh, a1h, acc[1][t], 0, 0, 0);
                    if (WLO) {
                        bf8_t wl = WLp[(kc * NT_TOT + tg) * 64];
                        acc[0][t] = __builtin_amdgcn_mfma_f32_16x16x32_bf16(wl, a0h, acc[0][t], 0, 0, 0);
                        acc[1][t] = __builtin_amdgcn_mfma_f32_16x16x32_bf16(wl, a1h, acc[1][t], 0, 0, 0);
                    }
                    if (ALO) {
                        acc[0][t] = __builtin_amdgcn_mfma_f32_16x16x32_bf16(wh, a0l, acc[0][t], 0, 0, 0);
                        acc[1][t] = __builtin_amdgcn_mfma_f32_16x16x32_bf16(wh, a1l, acc[1][t], 0, 0, 0);
                    }
                }
            }
        }
    }

    #pragma unroll
    for (int rt = 0; rt < 2; ++rt) {
        if (MODE == 0) {
            int m = (rt0 + rt) * 16 + (lane & 15);
            #pragma unroll
            for (int t = 0; t < NT_W; ++t) {
                int tg = t0 + t;
                int nb = tg * 16 + ((lane >> 4) << 2);
                if (tg < NT_TOT && nb + 4 <= NV) {
                    float4 bb = *(const float4*)(bias + nb);
                    f32x4 a = acc[rt][t];
                    float4 v = {a[0] + bb.x, a[1] + bb.y, a[2] + bb.z, a[3] + bb.w};
                    *(float4*)(C + (size_t)m * ldc + nb) = v;
                }
            }
        } else if (MODE == 1) {
            int m = (rt0 + rt) * 16 + (lane & 15);
            #pragma unroll
            for (int t = 0; t < NT_W; ++t) {
                int tg = t0 + t;
                if (tg < NT_TOT) {
                    int nb = tg * 16 + ((lane >> 4) << 2);
                    float4 bb = *(const float4*)(bias + nb);
                    f32x4 a = acc[rt][t];
                    float v[4];
                    v[0] = gelu_exact(a[0] + bb.x); v[1] = gelu_exact(a[1] + bb.y);
                    v[2] = gelu_exact(a[2] + bb.z); v[3] = gelu_exact(a[3] + bb.w);
                    unsigned hh[4];
                    #pragma unroll
                    for (int i = 0; i < 4; ++i) hh[i] = (unsigned)bf16c(v[i]);
                    uint2 hi = make_uint2(hh[0] | (hh[1] << 16), hh[2] | (hh[3] << 16));
                    int kco = nb >> 5, lp = (m & 15) + ((nb & 31) >> 3) * 16;
                    size_t fb = ((size_t)(rt0 + rt) * (NV / 32) + kco) * 512 + lp * 8 + (nb & 7);
                    *(uint2*)(OF + fb) = hi;
                }
            }
        } else if (MODE == 3) {
            // bf16 store into zero-padded [b][66][66][128]
            unsigned short* Cp = (unsigned short*)C;
            int m = (rt0 + rt) * 16 + (lane & 15);
            int bb_ = m >> 12, hwm = m & 4095;
            size_t rowb = (((size_t)bb_ * 66 + (hwm >> 6) + 1) * 66 + (hwm & 63) + 1) * 128;
            #pragma unroll
            for (int t = 0; t < NT_W; ++t) {
                int tg = t0 + t;
                int nb = tg * 16 + ((lane >> 4) << 2);
                if (tg < NT_TOT) {
                    float4 bb = *(const float4*)(bias + nb);
                    f32x4 a = acc[rt][t];
                    ushort4 v;
                    v.x = bf16c(a[0] + bb.x); v.y = bf16c(a[1] + bb.y);
                    v.z = bf16c(a[2] + bb.z); v.w = bf16c(a[3] + bb.w);
                    *(ushort4*)(Cp + rowb + nb) = v;
                }
            }
        } else if (MODE == 4) {
            // bf16 split store: offs (C, ld 144) and msk (C2, ld 72)
            unsigned short* Co = (unsigned short*)C;
            unsigned short* Cm = (unsigned short*)C2;
            int m = (rt0 + rt) * 16 + (lane & 15);
            #pragma unroll
            for (int t = 0; t < NT_W; ++t) {
                int tg = t0 + t;
                if (tg < NT_TOT) {
                    int nb = tg * 16 + ((lane >> 4) << 2);
                    f32x4 a = acc[rt][t];
                    if (nb < 144) {
                        float4 bb = *(const float4*)(bias + nb);
                        ushort4 v;
                        v.x = bf16c(a[0] + bb.x); v.y = bf16c(a[1] + bb.y);
                        v.z = bf16c(a[2] + bb.z); v.w = bf16c(a[3] + bb.w);
                        *(ushort4*)(Co + (size_t)m * 144 + nb) = v;
                    } else {
                        int col = nb - 144;
                        if (col + 4 <= 72) {
                            float4 bb = *(const float4*)(bias2 + col);
                            ushort4 v;
                            v.x = bf16c(a[0] + bb.x); v.y = bf16c(a[1] + bb.y);
                            v.z = bf16c(a[2] + bb.z); v.w = bf16c(a[3] + bb.w);
                            *(ushort4*)(Cm + (size_t)m * 72 + col) = v;
                        }
                    }
                }
            }
        } else {
            int m4 = (rt0 + rt) * 16 + ((lane >> 4) << 2);
            int b = m4 >> 12, hw = m4 & 4095;
            #pragma unroll
            for (int t = 0; t < NT_W; ++t) {
                int tg = t0 + t;
                if (tg < NT_TOT) {
                    int n = tg * 16 + (lane & 15);
                    float bb = bias[n];
                    f32x4 a = acc[rt][t];
                    float4 v = {a[0] + bb, a[1] + bb, a[2] + bb, a[3] + bb};
                    *(float4*)(C + (((size_t)(b * 128 + n)) << 12) + hw) = v;
                }
            }
        }
    }
}

template<int KDIM, int NT_TOT, int NT_W, int MODE, int NV, int ALO, int WLO>
__global__ __launch_bounds__(256) void k_fgemm(
    const unsigned short* __restrict__ AF, const unsigned short* __restrict__ WF,
    const float* __restrict__ bias, float* __restrict__ C, int ldc,
    unsigned short* __restrict__ OF, const float* __restrict__ bias2,
    float* __restrict__ C2)
{
    fgemm_body<KDIM, NT_TOT, NT_W, MODE, NV, ALO, WLO>(
        blockIdx.x, blockIdx.y, threadIdx.x, AF, WF, bias, C, ldc, OF, bias2, C2);
}

// K_bp: merged bngelu (2048 blocks) + proj GEMM (1024 blocks). grid 3072.
__global__ __launch_bounds__(256) void k_bp(
    const unsigned short* __restrict__ ydwb, const float* __restrict__ sc,
    const float* __restrict__ sh, unsigned short* __restrict__ x1f,
    const unsigned short* __restrict__ inpf, const unsigned short* __restrict__ wprojf,
    const float* __restrict__ bproj, unsigned short* __restrict__ xpad)
{
    int bid = blockIdx.x;
    if (bid < 2048) {
        bngelu_body(bid, threadIdx.x, ydwb, sc, sh, x1f);
    } else {
        int pbid = bid - 2048;
        fgemm_body<128, 8, 2, 3, 128, 0, 0>(pbid & 255, pbid >> 8, threadIdx.x,
            inpf, wprojf, bproj, (float*)xpad, 0, nullptr, nullptr, nullptr);
    }
}

// ---------------------------------------------------------------------------
// K6: DCNv3 core. thread = (pos, g), 16 channels. grid 1024, block 256.
// bf16 xpad gathers, bf16 offs/msk inputs, clamped addressing.
// Softmax once per (pos,g). Output packed as fc1 hi-only A-frags.
// ---------------------------------------------------------------------------
__global__ __launch_bounds__(256) void k_dcn(
    const unsigned short* __restrict__ xpad, const unsigned short* __restrict__ offs,
    const unsigned short* __restrict__ msk, unsigned short* __restrict__ dcnf)
{
    int u = blockIdx.x * 256 + threadIdx.x;  // 32768*8
    int g = u & 7;
    int pos = u >> 3;
    int b = pos >> 12, hw = pos & 4095, h = hw >> 6, w = hw & 63;

    const unsigned short* ml = msk + (size_t)pos * 72 + g * 9;
    float e[9];
    float mx = -1e30f;
    #pragma unroll
    for (int p = 0; p < 9; ++p) { e[p] = bfd((unsigned)ml[p]); mx = fmaxf(mx, e[p]); }
    float ssum = 0.f;
    #pragma unroll
    for (int p = 0; p < 9; ++p) { e[p] = __expf(e[p] - mx); ssum += e[p]; }
    float inv = 1.0f / ssum;

    const unsigned short* ob = offs + (size_t)pos * 144 + g * 18;
    const unsigned short* xb = xpad + (size_t)b * 557568 + g * 16;  // 66*66*128/b

    float acc[16];
    #pragma unroll
    for (int i = 0; i < 16; ++i) acc[i] = 0.f;

    #pragma unroll
    for (int p = 0; p < 9; ++p) {
        unsigned dpair = *(const unsigned*)(ob + p * 2);
        float dx = bfd(dpair);
        float dy = __builtin_bit_cast(float, dpair & 0xFFFF0000u);
        float px = (float)(w + (p % 3)) + dx;   // padded-grid coords
        float py = (float)(h + (p / 3)) + dy;
        float x0f = floorf(px), y0f = floorf(py);
        float wx = px - x0f, wy = py - y0f;
        int ix = (int)x0f, iy = (int)y0f;
        int ix0 = max(min(ix, 65), 0),     ix1 = max(min(ix + 1, 65), 0);
        int iy0 = max(min(iy, 65), 0),     iy1 = max(min(iy + 1, 65), 0);
        int r0 = iy0 * 66, r1 = iy1 * 66;

        float mp  = e[p] * inv;
        float w11 = wy * wx * mp;
        float w10 = wy * mp - w11;
        float w01 = wx * mp - w11;
        float w00 = mp - w01 - w10 - w11;

        const unsigned short* c00 = xb + (size_t)(r0 + ix0) * 128;
        const unsigned short* c01 = xb + (size_t)(r0 + ix1) * 128;
        const unsigned short* c10 = xb + (size_t)(r1 + ix0) * 128;
        const unsigned short* c11 = xb + (size_t)(r1 + ix1) * 128;

        uint4 a00 = *(const uint4*)(c00), b00 = *(const uint4*)(c00 + 8);
        uint4 a01 = *(const uint4*)(c01), b01 = *(const uint4*)(c01 + 8);
        uint4 a10 = *(const uint4*)(c10), b10 = *(const uint4*)(c10 + 8);
        uint4 a11 = *(const uint4*)(c11), b11 = *(const uint4*)(c11 + 8);

        ufma(acc,     a00, w00); ufma(acc + 8, b00, w00);
        ufma(acc,     a01, w01); ufma(acc + 8, b01, w01);
        ufma(acc,     a10, w10); ufma(acc + 8, b10, w10);
        ufma(acc,     a11, w11); ufma(acc + 8, b11, w11);
    }

    // pack 16 channels as two hi-only frag groups
    int rt = pos >> 4, kc = g >> 1;
    int lp0 = (pos & 15) + (g & 1) * 32;
    size_t fb = ((size_t)rt * 4 + kc) * 512 + (size_t)lp0 * 8;
    uint4 hiA = pack8hi(acc);
    uint4 hiB = pack8hi(acc + 8);
    *(uint4*)(dcnf + fb)       = hiA;
    *(uint4*)(dcnf + fb + 128) = hiB;   // lp0+16
}

// ---------------------------------------------------------------------------
extern "C" void kernel_launch(void* const* d_in, const int* in_sizes, int n_in,
                              void* d_out, int out_size, void* d_ws, size_t ws_size,
                              hipStream_t stream)
{
    const float* inp   = (const float*)d_in[0];
    const float* wproj = (const float*)d_in[1];
    const float* bproj = (const float*)d_in[2];
    const float* dww   = (const float*)d_in[3];
    const float* dwb   = (const float*)d_in[4];
    const float* gamma = (const float*)d_in[5];
    const float* beta  = (const float*)d_in[6];
    const float* woff  = (const float*)d_in[7];
    const float* boff  = (const float*)d_in[8];
    const float* wmask = (const float*)d_in[9];
    const float* bmask = (const float*)d_in[10];
    const float* wfc1  = (const float*)d_in[11];
    const float* bfc1  = (const float*)d_in[12];
    const float* wfc2  = (const float*)d_in[13];
    const float* bfc2  = (const float*)d_in[14];
    float* out = (float*)d_out;
    float* ws  = (float*)d_ws;

    // Region P: xpad (bf16) + offs (bf16); later hdnf (fc1 hi-only frags)
    unsigned short* xpad = (unsigned short*)ws;              // 4,460,544 ush [proj..dcn]
    unsigned short* offs = (unsigned short*)(ws + 2230272);  // 4,718,592 ush [offmask..dcn]
    unsigned short* hdnf = (unsigned short*)ws;              // 8,388,608 ush [fc1..fc2]
    // Region A at ws+9179136: inpf [pd..bp-proj], dcnf [dcn..fc1]
    unsigned short* inpf  = (unsigned short*)(ws + 9179136);   // 4,194,304 ush hi-only
    unsigned short* dcnf  = (unsigned short*)(ws + 9179136);   // 4,194,304 ush hi-only
    unsigned short* x1f   = (unsigned short*)(ws + 13373440);  // 4,194,304 ush hi-only [bp..offmask]
    unsigned short* ydwb  = (unsigned short*)(ws + 15470592);  // 4,194,304 ush bf16 [pd..bp]
    // Rest
    unsigned short* msk = (unsigned short*)(ws + 17567744);  // 2,359,296 ush
    float* psum = ws + 19927040;                         // 65,536 f
    float* psq  = ws + 19992576;                         // 65,536 f
    float* scs  = ws + 20058112;                         // 128 f
    float* shs  = ws + 20058240;                         // 128 f
    unsigned short* wfr = (unsigned short*)(ws + 20058368);  // 176,128 ush

    unsigned short* wproj_f = wfr;            // hi-only, 16384
    unsigned short* womb_f  = wfr + 16384;    // hi-only combined, 28672
    unsigned short* wfc1_f  = wfr + 45056;    // hi/lo, 65536
    unsigned short* wfc2_f  = wfr + 110592;   // hi/lo, 65536

    k_pd<<<2744, 256, 0, stream>>>(inp, inpf, xpad, wproj, woff, wmask, wfc1, wfc2,
                                   wfr, dww, dwb, ydwb, psum, psq);
    k_bnstats<<<128, 256, 0, stream>>>(psum, psq, gamma, beta, scs, shs);
    k_bp<<<3072, 256, 0, stream>>>(ydwb, scs, shs, x1f, inpf, wproj_f, bproj, xpad);
    k_fgemm<128, 14, 4, 4, 224, 0, 0><<<dim3(256, 4), 256, 0, stream>>>(x1f, womb_f, boff, (float*)offs, 144, nullptr, bmask, (float*)msk);
    k_dcn<<<1024, 256, 0, stream>>>(xpad, offs, msk, dcnf);
    k_fgemm<128, 16, 4, 1, 256, 0, 1><<<dim3(256, 4), 256, 0, stream>>>(dcnf, wfc1_f, bfc1, nullptr, 0, hdnf, nullptr, nullptr);
    k_fgemm<256,  8, 4, 2, 128, 0, 1><<<dim3(256, 2), 256, 0, stream>>>(hdnf, wfc2_f, bfc2, out, 0, nullptr, nullptr, nullptr);
}